// Round 11
// baseline (479.961 us; speedup 1.0000x reference)
//
#include <hip/hip_runtime.h>
#include <math.h>
#include <stdint.h>

#define BB 2
#define SS 2048
#define DD 512
#define HH 1024
#define MMETA 64
#define KCONV 4
#define NHH 8
#define DHH 64
#define WINN 256
#define TT (MMETA + SS)     // 2112
#define BT (BB * TT)        // 4224
#define QKV_N 1536

typedef __attribute__((ext_vector_type(8))) short short8v;   // 8 bf16 = 4 VGPR
typedef __attribute__((ext_vector_type(4))) float f32x4;

__device__ __forceinline__ unsigned short f2bf(float f) {
    union { float f; unsigned u; } c; c.f = f;
    unsigned u = c.u;
    unsigned r = (u + 0x7fffu + ((u >> 16) & 1u)) >> 16;   // RNE
    return (unsigned short)r;
}
__device__ __forceinline__ float bf2f(unsigned short h) {
    union { unsigned u; float f; } c; c.u = ((unsigned)h) << 16;
    return c.f;
}

__device__ __forceinline__ void gload_lds16(const void* g, void* l) {
    __builtin_amdgcn_global_load_lds(
        (const __attribute__((address_space(1))) unsigned int*)g,
        (__attribute__((address_space(3))) unsigned int*)l, 16, 0, 0);
}

template<int N>
__device__ __forceinline__ void vm_wait() {
    if constexpr (N == 0)       asm volatile("s_waitcnt vmcnt(0)" ::: "memory");
    else if constexpr (N == 8)  asm volatile("s_waitcnt vmcnt(8)" ::: "memory");
    else if constexpr (N == 16) asm volatile("s_waitcnt vmcnt(16)" ::: "memory");
    else static_assert(N == 0, "unsupported vmcnt");
}

// ---------------------------------------------------------------------------
// mega weight transpose+split: all 9 weights in one dispatch
// ---------------------------------------------------------------------------
struct WJobs {
    const float* W[9];
    unsigned short* Wh[9];
    unsigned short* Wl[9];
    int K[9];
    int N[9];
    int base[10];
};

__global__ __launch_bounds__(256) void wsplit_all_k(WJobs jb)
{
    __shared__ float tile[64][65];
    const int t = blockIdx.x;
    int j = 0;
    while (t >= jb.base[j + 1]) ++j;
    const int local = t - jb.base[j];
    const int K = jb.K[j], N = jb.N[j];
    const int nx = N >> 6;
    const int k0 = (local / nx) * 64, n0 = (local % nx) * 64;
    const float* W = jb.W[j];
    unsigned short* Wh = jb.Wh[j];
    unsigned short* Wl = jb.Wl[j];

    const int tid = threadIdx.x;
    #pragma unroll
    for (int i = 0; i < 16; ++i) {
        int lin = i * 256 + tid;
        int kr = lin >> 6, nc = lin & 63;
        tile[kr][nc] = W[(size_t)(k0 + kr) * N + n0 + nc];
    }
    __syncthreads();
    #pragma unroll
    for (int i = 0; i < 16; ++i) {
        int lin = i * 256 + tid;
        int nr = lin >> 6, kc = lin & 63;
        float v = tile[kc][nr];
        unsigned short hi = f2bf(v);
        size_t idx = (size_t)(n0 + nr) * K + k0 + kc;
        Wh[idx] = hi;
        Wl[idx] = f2bf(v - bf2f(hi));
    }
}

// ---------------------------------------------------------------------------
__global__ __launch_bounds__(256) void bias_concat_k(
    const float* __restrict__ bq, const float* __restrict__ bk,
    const float* __restrict__ bv, float* __restrict__ o)
{
    int i = blockIdx.x * 256 + threadIdx.x;
    if (i >= QKV_N) return;
    float v;
    if (i < 512) v = bq[i];
    else if (i < 1024) v = bk[i - 512];
    else v = bv[i - 1024];
    o[i] = v;
}

// ---------------------------------------------------------------------------
__global__ __launch_bounds__(256) void build_xm_k(
    const float* __restrict__ x, const float* __restrict__ meta,
    unsigned short* __restrict__ xh, unsigned short* __restrict__ xl)
{
    int idx = blockIdx.x * 256 + threadIdx.x;   // float4 index over BT*128
    if (idx >= BT * 128) return;
    int row = idx >> 7, c4 = idx & 127;
    int b = row >= TT;
    int t = row - b * TT;
    float4 v = (t < MMETA) ? ((const float4*)(meta + (size_t)t * DD))[c4]
                           : ((const float4*)(x + ((size_t)b * SS + (t - MMETA)) * DD))[c4];
    ushort4 h, lo;
    h.x = f2bf(v.x); lo.x = f2bf(v.x - bf2f(h.x));
    h.y = f2bf(v.y); lo.y = f2bf(v.y - bf2f(h.y));
    h.z = f2bf(v.z); lo.z = f2bf(v.z - bf2f(h.z));
    h.w = f2bf(v.w); lo.w = f2bf(v.w - bf2f(h.w));
    ((ushort4*)xh)[idx] = h;
    ((ushort4*)xl)[idx] = lo;
}

// ---------------------------------------------------------------------------
// bf16x3 MFMA GEMM, block 128x256, 2x2 waves (wave tile 64x128).
//   A hi/lo: global -> registers directly (double-buffered reg sets).
//   B hi/lo: global -> LDS, triple-buffered, staged 2 tiles ahead,
//            counted vmcnt (T4).
//   EPI: 0 bias->fp32; 1 silu->hi/lo; 2 silu+res->hi/lo; 3 bias->hi/lo;
//        4 bias->hi/lo cols<1024 + transposed vt write cols>=1024
// ---------------------------------------------------------------------------
template<int GN, int EPI, bool DROPMETA>
__global__ __launch_bounds__(256, 1) void gemm_mfma_k(
    const unsigned short* __restrict__ Ah, const unsigned short* __restrict__ Al,
    const unsigned short* __restrict__ Wh, const unsigned short* __restrict__ Wl,
    const float* __restrict__ bias,
    const unsigned short* __restrict__ resh, const unsigned short* __restrict__ resl,
    float* __restrict__ outf, unsigned short* __restrict__ outh,
    unsigned short* __restrict__ outl,
    unsigned short* __restrict__ vth, unsigned short* __restrict__ vtl,
    int K, int N)
{
    constexpr int BBY = 256 * 64;        // 16 KB per half (hi or lo)
    constexpr int BUFB = 2 * BBY;        // 32 KB per k-tile buffer
    __shared__ short8v smem_v[(3 * BUFB) / 16];   // 96 KB
    char* smem = (char*)smem_v;

    // bijective XCD-chunk swizzle (m204); NWG = 33*GN
    constexpr int NWG = 33 * GN;
    constexpr int qch = NWG / 8, rch = NWG % 8;
    const int orig = blockIdx.x;
    const int xcd = orig & 7;
    const int swz = (xcd < rch ? xcd * (qch + 1) : rch * (qch + 1) + (xcd - rch) * qch)
                    + (orig >> 3);
    const int row0 = (swz / GN) * 128;
    const int n0 = (swz % GN) * 256;

    const int tid = threadIdx.x;
    const int l = tid & 63, wid = tid >> 6;
    const int wm = wid >> 1, wn = wid & 1;
    const int lr = l & 15, lg = l >> 4;

    const char* Whg = (const char*)Wh + (size_t)n0 * K * 2;
    const char* Wlg = (const char*)Wl + (size_t)n0 * K * 2;

    // A per-lane row pointers (4 fragments x hi/lo)
    const unsigned short* aph[4];
    const unsigned short* apl[4];
    #pragma unroll
    for (int mf = 0; mf < 4; ++mf) {
        int r = row0 + wm * 64 + mf * 16 + lr;
        aph[mf] = Ah + (size_t)r * K + lg * 8;
        apl[mf] = Al + (size_t)r * K + lg * 8;
    }

    // B LDS read offsets (conflict-free sigma = (r>>1)&3)
    int b_off[8];
    #pragma unroll
    for (int nf = 0; nf < 8; ++nf) {
        int r = wn * 128 + nf * 16 + lr;
        b_off[nf] = r * 64 + ((lg * 16) ^ (((r >> 1) & 3) << 4));
    }

    f32x4 acc[4][8];
    #pragma unroll
    for (int mf = 0; mf < 4; ++mf)
        #pragma unroll
        for (int nf = 0; nf < 8; ++nf) acc[mf][nf] = (f32x4){0.f, 0.f, 0.f, 0.f};

    const int NT = K / 32;

    auto stageB = [&](int buf, int t) {
        char* lb = smem + buf * BUFB;
        const size_t kb = (size_t)t * 64;
        #pragma unroll
        for (int it = 0; it < 4; ++it) {
            int off = (it * 256 + tid) * 16;
            int row = off >> 6;
            int sc = (off & 63) ^ (((row >> 1) & 3) << 4);
            size_t gb = (size_t)row * (K * 2) + kb + sc;
            gload_lds16(Whg + gb, lb + off);
            gload_lds16(Wlg + gb, lb + BBY + off);
        }
    };

    short8v aAh[4], aAl[4], aBh[4], aBl[4];

    // prologue: B tiles 0,1 staged; A tile 0 in regs
    stageB(0, 0);
    stageB(1, 1);
    #pragma unroll
    for (int mf = 0; mf < 4; ++mf) {
        aAh[mf] = *(const short8v*)(aph[mf]);
        aAl[mf] = *(const short8v*)(apl[mf]);
    }

    auto body = [&](int t, short8v (&aCh)[4], short8v (&aCl)[4],
                    short8v (&aNh)[4], short8v (&aNl)[4]) {
        if (t + 2 < NT) stageB((t + 2) % 3, t + 2);            // 8 VMEM
        if (t + 1 < NT) {
            #pragma unroll
            for (int mf = 0; mf < 4; ++mf) {                   // 8 VMEM
                aNh[mf] = *(const short8v*)(aph[mf] + (size_t)(t + 1) * 32);
                aNl[mf] = *(const short8v*)(apl[mf] + (size_t)(t + 1) * 32);
            }
        }
        if (t + 2 < NT)      vm_wait<16>();   // tile t (B stores + A regs) done
        else if (t + 1 < NT) vm_wait<8>();
        else                 vm_wait<0>();
        __builtin_amdgcn_s_barrier();
        __builtin_amdgcn_sched_barrier(0);

        char* lb = smem + (t % 3) * BUFB;
        __builtin_amdgcn_s_setprio(1);
        #pragma unroll
        for (int nf = 0; nf < 8; ++nf) {
            short8v bh = *(const short8v*)(lb + b_off[nf]);
            short8v bl = *(const short8v*)(lb + BBY + b_off[nf]);
            #pragma unroll
            for (int mf = 0; mf < 4; ++mf) {
                acc[mf][nf] = __builtin_amdgcn_mfma_f32_16x16x32_bf16(aCh[mf], bh, acc[mf][nf], 0, 0, 0);
                acc[mf][nf] = __builtin_amdgcn_mfma_f32_16x16x32_bf16(aCh[mf], bl, acc[mf][nf], 0, 0, 0);
                acc[mf][nf] = __builtin_amdgcn_mfma_f32_16x16x32_bf16(aCl[mf], bh, acc[mf][nf], 0, 0, 0);
            }
        }
        __builtin_amdgcn_s_setprio(0);
        __builtin_amdgcn_s_barrier();      // reads of buf (t%3) done before restage
    };

    for (int t = 0; t < NT; t += 2) {
        body(t,     aAh, aAl, aBh, aBl);
        body(t + 1, aBh, aBl, aAh, aAl);
    }

    // epilogue: C/D layout col = lane&15, row = (lane>>4)*4 + reg
    #pragma unroll
    for (int mf = 0; mf < 4; ++mf) {
        #pragma unroll
        for (int nf = 0; nf < 8; ++nf) {
            int col = n0 + wn * 128 + nf * 16 + lr;
            float bv = bias[col];
            if (EPI == 4 && col >= 1024) {
                unsigned short hv[4], lv[4];
                #pragma unroll
                for (int j = 0; j < 4; ++j) {
                    float v = acc[mf][nf][j] + bv;
                    unsigned short hi = f2bf(v);
                    hv[j] = hi; lv[j] = f2bf(v - bf2f(hi));
                }
                int dg = col - 1024;
                size_t tok = (size_t)row0 + wm * 64 + mf * 16 + lg * 4;
                *(ushort4*)(vth + (size_t)dg * BT + tok) = *(ushort4*)hv;
                *(ushort4*)(vtl + (size_t)dg * BT + tok) = *(ushort4*)lv;
            } else {
                #pragma unroll
                for (int j = 0; j < 4; ++j) {
                    int row = row0 + wm * 64 + mf * 16 + lg * 4 + j;
                    float v = acc[mf][nf][j] + bv;
                    if (EPI == 1 || EPI == 2) v = v / (1.f + __expf(-v));
                    size_t idx = (size_t)row * N + col;
                    if (EPI == 2) v += bf2f(resh[idx]) + bf2f(resl[idx]);
                    if (EPI == 0) {
                        if (DROPMETA) {
                            int b = row >= TT;
                            int t2 = row - b * TT;
                            if (t2 >= MMETA)
                                outf[((size_t)b * SS + (t2 - MMETA)) * N + col] = v;
                        } else {
                            outf[idx] = v;
                        }
                    } else {
                        unsigned short hi = f2bf(v);
                        outh[idx] = hi;
                        outl[idx] = f2bf(v - bf2f(hi));
                    }
                }
            }
        }
    }
}

// ---------------------------------------------------------------------------
__global__ __launch_bounds__(256) void conv_norm_k(
    const float* __restrict__ qlin, const float* __restrict__ convw,
    unsigned short* __restrict__ qh, unsigned short* __restrict__ ql)
{
    const int row = blockIdx.x;
    const int b = row >= TT;
    const int t = row - b * TT;
    const int tid = threadIdx.x;

    float vals[2];
    float ss = 0.f;
    #pragma unroll
    for (int e = 0; e < 2; ++e) {
        int d = tid + e * 256;
        float acc = 0.f;
        #pragma unroll
        for (int k = 0; k < KCONV; ++k) {
            int tt = t - (KCONV - 1) + k;
            if (tt >= 0)
                acc += qlin[((size_t)b * TT + tt) * DD + d] * convw[k * DD + d];
        }
        vals[e] = acc;
        ss += acc * acc;
    }
    #pragma unroll
    for (int off = 32; off > 0; off >>= 1)
        ss += __shfl_xor(ss, off);
    __shared__ float red[4];
    if ((tid & 63) == 0) red[tid >> 6] = ss;
    __syncthreads();
    float total = red[0] + red[1] + red[2] + red[3];
    float inv = 1.f / fmaxf(sqrtf(total), 1e-12f);
    #pragma unroll
    for (int e = 0; e < 2; ++e) {
        int d = tid + e * 256;
        float v = vals[e] * inv;
        unsigned short hi = f2bf(v);
        qh[(size_t)row * DD + d] = hi;
        ql[(size_t)row * DD + d] = f2bf(v - bf2f(hi));
    }
}

// ---------------------------------------------------------------------------
// Flash sliding-window attention, MFMA, V^T staged from global.
// ---------------------------------------------------------------------------
__global__ __launch_bounds__(256, 2) void swa_flash_k(
    const unsigned short* __restrict__ qkvh, const unsigned short* __restrict__ qkvl,
    const unsigned short* __restrict__ vth, const unsigned short* __restrict__ vtl,
    unsigned short* __restrict__ oh, unsigned short* __restrict__ ol)
{
    // LDS: Kh 8192 | Kl 8192 | Vh 8192 | Vl 8192 | P 4x2304
    __shared__ short8v lds_v[41984 / 16];
    char* lds = (char*)lds_v;
    char* Kh_lds = lds;
    char* Kl_lds = lds + 8192;
    char* Vh_lds = lds + 16384;
    char* Vl_lds = lds + 24576;
    char* P_lds  = lds + 32768;

    const int tid = threadIdx.x;
    const int lane = tid & 63, w = tid >> 6;
    const int l15 = lane & 15, lg = lane >> 4;
    const int q0 = blockIdx.x * 64;
    const int h = blockIdx.y, b = blockIdx.z;
    const int rowbase = b * TT;

    const int qrow = rowbase + q0 + w * 16 + l15;
    short8v qhf[2], qlf[2];
    #pragma unroll
    for (int kh = 0; kh < 2; ++kh) {
        size_t off = (size_t)qrow * QKV_N + h * 64 + kh * 32 + lg * 8;
        qhf[kh] = *(const short8v*)(qkvh + off);
        qlf[kh] = *(const short8v*)(qkvl + off);
    }

    f32x4 o_acc[4];
    #pragma unroll
    for (int td = 0; td < 4; ++td) o_acc[td] = (f32x4){0.f, 0.f, 0.f, 0.f};
    float m_r[4], l_r[4];
    #pragma unroll
    for (int r = 0; r < 4; ++r) { m_r[r] = -1e30f; l_r[r] = 0.f; }

    char* Pw = P_lds + w * 2304;   // per-wave [16][72] bf16

    for (int kt = 0; kt < 5; ++kt) {
        const int kst = q0 - 256 + kt * 64;
        if (kst + 64 <= 0) continue;
        __syncthreads();
        #pragma unroll
        for (int it = 0; it < 2; ++it) {
            int lin = it * 256 + tid;
            int r = lin >> 3, seg = lin & 7;
            int colb = (seg * 16) ^ ((r & 7) << 4);
            size_t gb = ((size_t)(rowbase + kst + r) * QKV_N + 512 + h * 64) * 2 + colb;
            gload_lds16((const char*)qkvh + gb, Kh_lds + lin * 16);
            gload_lds16((const char*)qkvl + gb, Kl_lds + lin * 16);
        }
        #pragma unroll
        for (int it = 0; it < 2; ++it) {
            int lin = it * 256 + tid;
            int dd = lin >> 3, seg = lin & 7;
            int colb = (seg * 16) ^ ((dd & 7) << 4);
            size_t gb = ((size_t)(h * 64 + dd) * BT + rowbase + kst) * 2 + colb;
            gload_lds16((const char*)vth + gb, Vh_lds + lin * 16);
            gload_lds16((const char*)vtl + gb, Vl_lds + lin * 16);
        }
        __syncthreads();

        f32x4 s_fr[4];
        #pragma unroll
        for (int tj = 0; tj < 4; ++tj) s_fr[tj] = (f32x4){0.f, 0.f, 0.f, 0.f};
        #pragma unroll
        for (int tj = 0; tj < 4; ++tj) {
            int j = tj * 16 + l15;
            #pragma unroll
            for (int kh = 0; kh < 2; ++kh) {
                int colb = (kh * 64 + lg * 16) ^ ((j & 7) << 4);
                short8v kbh = *(const short8v*)(Kh_lds + j * 128 + colb);
                short8v kbl = *(const short8v*)(Kl_lds + j * 128 + colb);
                s_fr[tj] = __builtin_amdgcn_mfma_f32_16x16x32_bf16(qhf[kh], kbh, s_fr[tj], 0, 0, 0);
                s_fr[tj] = __builtin_amdgcn_mfma_f32_16x16x32_bf16(qhf[kh], kbl, s_fr[tj], 0, 0, 0);
                s_fr[tj] = __builtin_amdgcn_mfma_f32_16x16x32_bf16(qlf[kh], kbh, s_fr[tj], 0, 0, 0);
            }
        }
        #pragma unroll
        for (int tj = 0; tj < 4; ++tj) {
            int j = kst + tj * 16 + l15;
            #pragma unroll
            for (int r = 0; r < 4; ++r) {
                int i = q0 + w * 16 + lg * 4 + r;
                bool valid = (j <= i) && (i - j < WINN);
                s_fr[tj][r] = valid ? s_fr[tj][r] * 0.125f : -1e30f;
            }
        }
        float mx[4];
        #pragma unroll
        for (int r = 0; r < 4; ++r) {
            mx[r] = fmaxf(fmaxf(s_fr[0][r], s_fr[1][r]), fmaxf(s_fr[2][r], s_fr[3][r]));
            #pragma unroll
            for (int msk = 1; msk <= 8; msk <<= 1)
                mx[r] = fmaxf(mx[r], __shfl_xor(mx[r], msk));
            float mn = fmaxf(m_r[r], mx[r]);
            float sc = __expf(m_r[r] - mn);
            m_r[r] = mn;
            l_r[r] *= sc;
            #pragma unroll
            for (int td = 0; td < 4; ++td) o_acc[td][r] *= sc;
        }
        float rs[4] = {0.f, 0.f, 0.f, 0.f};
        #pragma unroll
        for (int tj = 0; tj < 4; ++tj) {
            #pragma unroll
            for (int r = 0; r < 4; ++r) {
                float p = __expf(s_fr[tj][r] - m_r[r]);
                rs[r] += p;
                ((unsigned short*)Pw)[(lg * 4 + r) * 72 + tj * 16 + l15] = f2bf(p);
            }
        }
        #pragma unroll
        for (int r = 0; r < 4; ++r) {
            #pragma unroll
            for (int msk = 1; msk <= 8; msk <<= 1)
                rs[r] += __shfl_xor(rs[r], msk);
            l_r[r] += rs[r];
        }
        short8v pa[2];
        #pragma unroll
        for (int jh = 0; jh < 2; ++jh)
            pa[jh] = *(const short8v*)(Pw + l15 * 144 + jh * 64 + lg * 16);
        #pragma unroll
        for (int td = 0; td < 4; ++td) {
            int drow = td * 16 + l15;
            #pragma unroll
            for (int jh = 0; jh < 2; ++jh) {
                int colb = (jh * 64 + lg * 16) ^ ((drow & 7) << 4);
                short8v vfh = *(const short8v*)(Vh_lds + drow * 128 + colb);
                short8v vfl = *(const short8v*)(Vl_lds + drow * 128 + colb);
                o_acc[td] = __builtin_amdgcn_mfma_f32_16x16x32_bf16(pa[jh], vfh, o_acc[td], 0, 0, 0);
                o_acc[td] = __builtin_amdgcn_mfma_f32_16x16x32_bf16(pa[jh], vfl, o_acc[td], 0, 0, 0);
            }
        }
    }

    #pragma unroll
    for (int r = 0; r < 4; ++r) {
        float inv = 1.f / l_r[r];
        int row = rowbase + q0 + w * 16 + lg * 4 + r;
        #pragma unroll
        for (int td = 0; td < 4; ++td) {
            float v = o_acc[td][r] * inv;
            size_t idx = (size_t)row * DD + h * 64 + td * 16 + l15;
            unsigned short hi = f2bf(v);
            oh[idx] = hi;
            ol[idx] = f2bf(v - bf2f(hi));
        }
    }
}

// ---------------------------------------------------------------------------
// Launch
// ---------------------------------------------------------------------------
extern "C" void kernel_launch(void* const* d_in, const int* in_sizes, int n_in,
                              void* d_out, int out_size, void* d_ws, size_t ws_size,
                              hipStream_t stream)
{
    const float* x       = (const float*)d_in[0];
    const float* meta    = (const float*)d_in[1];
    const float* qp_w    = (const float*)d_in[2];
    const float* qp_b    = (const float*)d_in[3];
    const float* qp_conv = (const float*)d_in[4];
    const float* w_in    = (const float*)d_in[5];
    const float* b_in    = (const float*)d_in[6];
    const float* w_hid   = (const float*)d_in[7];
    const float* b_hid   = (const float*)d_in[8];
    const float* w_out   = (const float*)d_in[9];
    const float* b_out   = (const float*)d_in[10];
    const float* wq      = (const float*)d_in[11];
    const float* bq      = (const float*)d_in[12];
    const float* wk      = (const float*)d_in[13];
    const float* bk      = (const float*)d_in[14];
    const float* wv      = (const float*)d_in[15];
    const float* bv      = (const float*)d_in[16];
    const float* wo      = (const float*)d_in[17];
    const float* bo      = (const float*)d_in[18];
    float* out = (float*)d_out;

    typedef unsigned short us;
    char* p = (char*)d_ws;
    auto alloc = [&](size_t n) { char* r = p; p += (n + 255) & ~(size_t)255; return r; };

    us* wqp_h   = (us*)alloc(512 * 512 * 2);   us* wqp_l   = (us*)alloc(512 * 512 * 2);
    us* win_h   = (us*)alloc(512 * 1024 * 2);  us* win_l   = (us*)alloc(512 * 1024 * 2);
    us* whid0_h = (us*)alloc(1024 * 1024 * 2); us* whid0_l = (us*)alloc(1024 * 1024 * 2);
    us* whid1_h = (us*)alloc(1024 * 1024 * 2); us* whid1_l = (us*)alloc(1024 * 1024 * 2);
    us* wout_h  = (us*)alloc(1024 * 512 * 2);  us* wout_l  = (us*)alloc(1024 * 512 * 2);
    us* wqkv_h  = (us*)alloc((size_t)QKV_N * 512 * 2);
    us* wqkv_l  = (us*)alloc((size_t)QKV_N * 512 * 2);
    us* wo_h    = (us*)alloc(512 * 512 * 2);   us* wo_l    = (us*)alloc(512 * 512 * 2);
    float* bqkv = (float*)alloc(QKV_N * 4);

    const size_t HALF = (size_t)BT * 512 * 2;   // 4.3 MB
    char* RA = alloc(2 * HALF);   // xm hi/lo  -> later ob hi/lo
    char* RB = alloc(2 * HALF);   // qlin fp32
    char* RC = alloc(2 * HALF);   // qn hi/lo -> r hi/lo
    char* RD = alloc(6 * HALF);   // ha hi/lo -> hc hi/lo -> qkv hi/lo (q,k only)
    char* RE = alloc(4 * HALF);   // hb hi/lo -> vt hi/lo ([512][BT] each)

    us* xm_h = (us*)RA;   us* xm_l = (us*)(RA + HALF);
    float* qlin = (float*)RB;
    us* qn_h = (us*)RC;   us* qn_l = (us*)(RC + HALF);
    us* ha_h = (us*)RD;   us* ha_l = (us*)(RD + 2 * HALF);
    us* hb_h = (us*)RE;   us* hb_l = (us*)(RE + 2 * HALF);
    us* hc_h = ha_h;      us* hc_l = ha_l;
    us* r_h  = qn_h;      us* r_l  = qn_l;
    us* qkv_h = (us*)RD;  us* qkv_l = (us*)(RD + 3 * HALF);
    us* vt_h  = (us*)RE;  us* vt_l  = (us*)(RE + HALF);
    us* ob_h = (us*)RA;   us* ob_l = (us*)(RA + HALF);

    // --- weight prep: one mega dispatch ---
    WJobs jb;
    const float* Ws[9]   = {qp_w, w_in, w_hid, w_hid + (size_t)1024 * 1024, w_out,
                            wq, wk, wv, wo};
    us* Whs[9] = {wqp_h, win_h, whid0_h, whid1_h, wout_h,
                  wqkv_h, wqkv_h + 512 * 512, wqkv_h + 2 * 512 * 512, wo_h};
    us* Wls[9] = {wqp_l, win_l, whid0_l, whid1_l, wout_l,
                  wqkv_l, wqkv_l + 512 * 512, wqkv_l + 2 * 512 * 512, wo_l};
    int Ks[9] = {512, 512, 1024, 1024, 1024, 512, 512, 512, 512};
    int Ns[9] = {512, 1024, 1024, 1024, 512, 512, 512, 512, 512};
    int acc_t = 0;
    for (int j = 0; j < 9; ++j) {
        jb.W[j] = Ws[j]; jb.Wh[j] = Whs[j]; jb.Wl[j] = Wls[j];
        jb.K[j] = Ks[j]; jb.N[j] = Ns[j];
        jb.base[j] = acc_t;
        acc_t += (Ks[j] / 64) * (Ns[j] / 64);
    }
    jb.base[9] = acc_t;    // 1088
    wsplit_all_k<<<acc_t, 256, 0, stream>>>(jb);
    bias_concat_k<<<6, 256, 0, stream>>>(bq, bk, bv, bqkv);

    // --- pipeline (block 128x256, grids 33*(N/256), no tail) ---
    build_xm_k<<<(BT * 128 + 255) / 256, 256, 0, stream>>>(x, meta, xm_h, xm_l);

    // qlin = xm @ qp_w + b (fp32): N=512, grid 66
    gemm_mfma_k<2, 0, false><<<66, 256, 0, stream>>>(
        xm_h, xm_l, wqp_h, wqp_l, qp_b, nullptr, nullptr, qlin, nullptr, nullptr,
        nullptr, nullptr, 512, 512);
    conv_norm_k<<<BT, 256, 0, stream>>>(qlin, qp_conv, qn_h, qn_l);
    // ha = silu(qn @ w_in + b_in): N=1024, grid 132
    gemm_mfma_k<4, 1, false><<<132, 256, 0, stream>>>(
        qn_h, qn_l, win_h, win_l, b_in, nullptr, nullptr, nullptr, ha_h, ha_l,
        nullptr, nullptr, 512, 1024);
    // hb = ha + silu(ha @ whid0 + b0): grid 132
    gemm_mfma_k<4, 2, false><<<132, 256, 0, stream>>>(
        ha_h, ha_l, whid0_h, whid0_l, b_hid, ha_h, ha_l, nullptr, hb_h, hb_l,
        nullptr, nullptr, 1024, 1024);
    // hc = hb + silu(hb @ whid1 + b1): grid 132
    gemm_mfma_k<4, 2, false><<<132, 256, 0, stream>>>(
        hb_h, hb_l, whid1_h, whid1_l, b_hid + HH, hb_h, hb_l, nullptr, hc_h, hc_l,
        nullptr, nullptr, 1024, 1024);
    // r = silu(hc @ w_out + b_out): N=512, grid 66
    gemm_mfma_k<2, 1, false><<<66, 256, 0, stream>>>(
        hc_h, hc_l, wout_h, wout_l, b_out, nullptr, nullptr, nullptr, r_h, r_l,
        nullptr, nullptr, 1024, 512);
    // fused q/k/v projection: N=1536, grid 198 (v transposed into vt)
    gemm_mfma_k<6, 4, false><<<198, 256, 0, stream>>>(
        r_h, r_l, wqkv_h, wqkv_l, bqkv, nullptr, nullptr, nullptr, qkv_h, qkv_l,
        vt_h, vt_l, 512, QKV_N);
    // flash sliding-window attention
    swa_flash_k<<<dim3(TT / 64, NHH, BB), 256, 0, stream>>>(qkv_h, qkv_l, vt_h, vt_l, ob_h, ob_l);
    // out = (ob @ wo + bo)[t >= M]: N=512, grid 66
    gemm_mfma_k<2, 0, true><<<66, 256, 0, stream>>>(
        ob_h, ob_l, wo_h, wo_l, bo, nullptr, nullptr, out, nullptr, nullptr,
        nullptr, nullptr, 512, 512);
}

// Round 12
// 248.550 us; speedup vs baseline: 1.9310x; 1.9310x over previous
//
#include <hip/hip_runtime.h>
#include <math.h>
#include <stdint.h>

#define BB 2
#define SS 2048
#define DD 512
#define HH 1024
#define MMETA 64
#define KCONV 4
#define NHH 8
#define DHH 64
#define WINN 256
#define TT (MMETA + SS)     // 2112
#define BT (BB * TT)        // 4224
#define QKV_N 1536

typedef __attribute__((ext_vector_type(8))) short short8v;   // 8 bf16 = 4 VGPR
typedef __attribute__((ext_vector_type(4))) float f32x4;

__device__ __forceinline__ unsigned short f2bf(float f) {
    union { float f; unsigned u; } c; c.f = f;
    unsigned u = c.u;
    unsigned r = (u + 0x7fffu + ((u >> 16) & 1u)) >> 16;   // RNE
    return (unsigned short)r;
}
__device__ __forceinline__ float bf2f(unsigned short h) {
    union { unsigned u; float f; } c; c.u = ((unsigned)h) << 16;
    return c.f;
}

__device__ __forceinline__ void gload_lds16(const void* g, void* l) {
    __builtin_amdgcn_global_load_lds(
        (const __attribute__((address_space(1))) unsigned int*)g,
        (__attribute__((address_space(3))) unsigned int*)l, 16, 0, 0);
}

// counted vmcnt wait (T4)
template<int N>
__device__ __forceinline__ void vm_wait() {
    if constexpr (N == 0)      asm volatile("s_waitcnt vmcnt(0)" ::: "memory");
    else if constexpr (N == 4) asm volatile("s_waitcnt vmcnt(4)" ::: "memory");
    else if constexpr (N == 6) asm volatile("s_waitcnt vmcnt(6)" ::: "memory");
    else static_assert(N == 0, "unsupported vmcnt");
}

// ---------------------------------------------------------------------------
// merged prep: 9x weight transpose+split  |  build_xm  |  bias concat
//   blocks [0,1088): wsplit; [1088,3200): build_xm; [3200,3206): bias
// ---------------------------------------------------------------------------
struct WJobs {
    const float* W[9];
    unsigned short* Wh[9];
    unsigned short* Wl[9];
    int K[9];
    int N[9];
    int base[10];
};

__global__ __launch_bounds__(256) void prep_all_k(
    WJobs jb,
    const float* __restrict__ x, const float* __restrict__ meta,
    unsigned short* __restrict__ xh, unsigned short* __restrict__ xl,
    const float* __restrict__ bq, const float* __restrict__ bk,
    const float* __restrict__ bv, float* __restrict__ bqkv)
{
    __shared__ float tile[64][65];
    const int bid = blockIdx.x;
    const int tid = threadIdx.x;

    if (bid < 1088) {
        int j = 0;
        while (bid >= jb.base[j + 1]) ++j;
        const int local = bid - jb.base[j];
        const int K = jb.K[j], N = jb.N[j];
        const int nx = N >> 6;
        const int k0 = (local / nx) * 64, n0 = (local % nx) * 64;
        const float* W = jb.W[j];
        unsigned short* Wh = jb.Wh[j];
        unsigned short* Wl = jb.Wl[j];
        #pragma unroll
        for (int i = 0; i < 16; ++i) {
            int lin = i * 256 + tid;
            int kr = lin >> 6, nc = lin & 63;
            tile[kr][nc] = W[(size_t)(k0 + kr) * N + n0 + nc];
        }
        __syncthreads();
        #pragma unroll
        for (int i = 0; i < 16; ++i) {
            int lin = i * 256 + tid;
            int nr = lin >> 6, kc = lin & 63;
            float v = tile[kc][nr];
            unsigned short hi = f2bf(v);
            size_t idx = (size_t)(n0 + nr) * K + k0 + kc;
            Wh[idx] = hi;
            Wl[idx] = f2bf(v - bf2f(hi));
        }
    } else if (bid < 3200) {
        int idx = (bid - 1088) * 256 + tid;   // float4 index over BT*128
        int row = idx >> 7, c4 = idx & 127;
        int b = row >= TT;
        int t = row - b * TT;
        float4 v = (t < MMETA) ? ((const float4*)(meta + (size_t)t * DD))[c4]
                               : ((const float4*)(x + ((size_t)b * SS + (t - MMETA)) * DD))[c4];
        ushort4 h, lo;
        h.x = f2bf(v.x); lo.x = f2bf(v.x - bf2f(h.x));
        h.y = f2bf(v.y); lo.y = f2bf(v.y - bf2f(h.y));
        h.z = f2bf(v.z); lo.z = f2bf(v.z - bf2f(h.z));
        h.w = f2bf(v.w); lo.w = f2bf(v.w - bf2f(h.w));
        ((ushort4*)xh)[idx] = h;
        ((ushort4*)xl)[idx] = lo;
    } else {
        int i = (bid - 3200) * 256 + tid;
        if (i < QKV_N) {
            float v;
            if (i < 512) v = bq[i];
            else if (i < 1024) v = bk[i - 512];
            else v = bv[i - 1024];
            bqkv[i] = v;
        }
    }
}

// ---------------------------------------------------------------------------
// bf16x3 MFMA GEMM with counted-vmcnt double-buffer pipeline (T4).
//   BM=64; BN in {64,128}; 1D grid of 66*GN blocks, XCD-chunk swizzled.
//   EPI: 0 bias->fp32; 1 silu->hi/lo; 2 res+silu->hi/lo;
//        4 bias->hi/lo for cols<1024, transposed vt write for cols>=1024
// ---------------------------------------------------------------------------
template<int BN, int GN, int EPI, bool DROPMETA>
__global__ __launch_bounds__(256, 3) void gemm_mfma_k(
    const unsigned short* __restrict__ Ah, const unsigned short* __restrict__ Al,
    const unsigned short* __restrict__ Wh, const unsigned short* __restrict__ Wl,
    const float* __restrict__ bias,
    const unsigned short* __restrict__ resh, const unsigned short* __restrict__ resl,
    float* __restrict__ outf, unsigned short* __restrict__ outh,
    unsigned short* __restrict__ outl,
    unsigned short* __restrict__ vth, unsigned short* __restrict__ vtl,
    int K, int N)
{
    constexpr int BM = 64;
    constexpr int MF = 2;              // wave covers 32 rows
    constexpr int NF = BN / 32;        // wave covers BN/2 cols
    constexpr int ABYTES = BM * 64;    // 4 KB per stream
    constexpr int BBYTES = BN * 64;
    constexpr int BUFB = 2 * ABYTES + 2 * BBYTES;
    constexpr int LOADS = 2 + (BN / 64) * 2;   // per-thread loads per stage
    __shared__ short8v smem_v[(2 * BUFB) / 16];
    char* smem = (char*)smem_v;

    // XCD-chunk swizzle (bijective since NWG % 8 == 0)
    constexpr int NWG = 66 * GN;
    const int orig = blockIdx.x;
    const int swz = (orig & 7) * (NWG >> 3) + (orig >> 3);
    const int row0 = (swz / GN) * BM;
    const int n0 = (swz % GN) * BN;

    const int tid = threadIdx.x;
    const int l = tid & 63, wid = tid >> 6;
    const int wm = wid >> 1, wn = wid & 1;
    const int lr = l & 15, lg = l >> 4;

    const char* Ahg0 = (const char*)Ah + (size_t)row0 * K * 2;
    const char* Alg0 = (const char*)Al + (size_t)row0 * K * 2;
    const char* Whg  = (const char*)Wh + (size_t)n0 * K * 2;
    const char* Wlg  = (const char*)Wl + (size_t)n0 * K * 2;

    // conflict-free swizzle: sigma(r) = (r>>1)&3 over the 4 16B segs of a row
    int a_off[MF], b_off[NF];
    #pragma unroll
    for (int mf = 0; mf < MF; ++mf) {
        int r = wm * 32 + mf * 16 + lr;
        a_off[mf] = r * 64 + ((lg * 16) ^ (((r >> 1) & 3) << 4));
    }
    #pragma unroll
    for (int nf = 0; nf < NF; ++nf) {
        int r = wn * (BN / 2) + nf * 16 + lr;
        b_off[nf] = r * 64 + ((lg * 16) ^ (((r >> 1) & 3) << 4));
    }

    f32x4 acc[MF][NF];
    #pragma unroll
    for (int mf = 0; mf < MF; ++mf)
        #pragma unroll
        for (int nf = 0; nf < NF; ++nf) acc[mf][nf] = (f32x4){0.f, 0.f, 0.f, 0.f};

    const int NT = K / 32;

    auto stage = [&](int buf, int t) {
        char* lb = smem + buf * BUFB;
        const size_t kb = (size_t)t * 64;
        {
            int off = tid * 16;
            int row = off >> 6;
            int sc = (off & 63) ^ (((row >> 1) & 3) << 4);
            size_t gb = (size_t)row * (K * 2) + kb + sc;
            gload_lds16(Ahg0 + gb, lb + off);
            gload_lds16(Alg0 + gb, lb + ABYTES + off);
        }
        #pragma unroll
        for (int it = 0; it < BBYTES / 4096; ++it) {
            int off = (it * 256 + tid) * 16;
            int row = off >> 6;
            int sc = (off & 63) ^ (((row >> 1) & 3) << 4);
            size_t gb = (size_t)row * (K * 2) + kb + sc;
            gload_lds16(Whg + gb, lb + 2 * ABYTES + off);
            gload_lds16(Wlg + gb, lb + 2 * ABYTES + BBYTES + off);
        }
    };

    stage(0, 0);

    int cur = 0;
    for (int t = 0; t < NT; ++t) {
        if (t + 1 < NT) {
            stage(cur ^ 1, t + 1);
            vm_wait<LOADS>();        // wait only for tile t's loads; t+1 stays in flight
        } else {
            vm_wait<0>();
        }
        __builtin_amdgcn_s_barrier();
        __builtin_amdgcn_sched_barrier(0);

        char* lb = smem + cur * BUFB;
        short8v ah[MF], al[MF], bh[NF], bl[NF];
        #pragma unroll
        for (int mf = 0; mf < MF; ++mf) {
            ah[mf] = *(const short8v*)(lb + a_off[mf]);
            al[mf] = *(const short8v*)(lb + ABYTES + a_off[mf]);
        }
        #pragma unroll
        for (int nf = 0; nf < NF; ++nf) {
            bh[nf] = *(const short8v*)(lb + 2 * ABYTES + b_off[nf]);
            bl[nf] = *(const short8v*)(lb + 2 * ABYTES + BBYTES + b_off[nf]);
        }
        __builtin_amdgcn_s_setprio(1);
        #pragma unroll
        for (int mf = 0; mf < MF; ++mf)
            #pragma unroll
            for (int nf = 0; nf < NF; ++nf) {
                acc[mf][nf] = __builtin_amdgcn_mfma_f32_16x16x32_bf16(ah[mf], bh[nf], acc[mf][nf], 0, 0, 0);
                acc[mf][nf] = __builtin_amdgcn_mfma_f32_16x16x32_bf16(ah[mf], bl[nf], acc[mf][nf], 0, 0, 0);
                acc[mf][nf] = __builtin_amdgcn_mfma_f32_16x16x32_bf16(al[mf], bh[nf], acc[mf][nf], 0, 0, 0);
            }
        __builtin_amdgcn_s_setprio(0);
        __builtin_amdgcn_s_barrier();    // all reads of buf[cur] done before overwrite
        cur ^= 1;
    }

    // epilogue: C/D layout col = lane&15, row = (lane>>4)*4 + reg
    #pragma unroll
    for (int mf = 0; mf < MF; ++mf) {
        #pragma unroll
        for (int nf = 0; nf < NF; ++nf) {
            int col = n0 + wn * (BN / 2) + nf * 16 + lr;
            float bv = bias[col];
            if (EPI == 4 && col >= 1024) {
                unsigned short hv[4], lv[4];
                #pragma unroll
                for (int j = 0; j < 4; ++j) {
                    float v = acc[mf][nf][j] + bv;
                    unsigned short hi = f2bf(v);
                    hv[j] = hi; lv[j] = f2bf(v - bf2f(hi));
                }
                int dg = col - 1024;
                size_t tok = (size_t)row0 + wm * 32 + mf * 16 + lg * 4;
                *(ushort4*)(vth + (size_t)dg * BT + tok) = *(ushort4*)hv;
                *(ushort4*)(vtl + (size_t)dg * BT + tok) = *(ushort4*)lv;
            } else {
                #pragma unroll
                for (int j = 0; j < 4; ++j) {
                    int row = row0 + wm * 32 + mf * 16 + lg * 4 + j;
                    float v = acc[mf][nf][j] + bv;
                    if (EPI == 1 || EPI == 2) v = v / (1.f + __expf(-v));
                    size_t idx = (size_t)row * N + col;
                    if (EPI == 2) v += bf2f(resh[idx]) + bf2f(resl[idx]);
                    if (EPI == 0) {
                        if (DROPMETA) {
                            int b = row >= TT;
                            int t2 = row - b * TT;
                            if (t2 >= MMETA)
                                outf[((size_t)b * SS + (t2 - MMETA)) * N + col] = v;
                        } else {
                            outf[idx] = v;
                        }
                    } else {
                        unsigned short hi = f2bf(v);
                        outh[idx] = hi;
                        outl[idx] = f2bf(v - bf2f(hi));
                    }
                }
            }
        }
    }
}

// ---------------------------------------------------------------------------
// causal depthwise conv (K=4) + L2 normalize; 8 rows/block with LDS row reuse.
//   One wave handles 2 rows; row data staged in LDS once (11 rows incl halo).
// ---------------------------------------------------------------------------
__global__ __launch_bounds__(256) void conv_norm8_k(
    const float* __restrict__ qlin, const float* __restrict__ convw,
    unsigned short* __restrict__ qh, unsigned short* __restrict__ ql)
{
    __shared__ float qs[11][512];
    const int tid = threadIdx.x;
    const int r0 = blockIdx.x * 8;               // 2112 % 8 == 0: no batch straddle
    const int b = r0 >= TT;
    const int bstart = b * TT;

    // stage rows r0-3 .. r0+7 (zeros before batch start)
    const float4* ql4 = (const float4*)qlin;
    for (int i = tid; i < 11 * 128; i += 256) {
        int lrow = i >> 7, c4 = i & 127;
        int grow = r0 - 3 + lrow;
        float4 v = (grow >= bstart) ? ql4[(size_t)grow * 128 + c4]
                                    : (float4){0.f, 0.f, 0.f, 0.f};
        ((float4*)qs[lrow])[c4] = v;
    }
    __syncthreads();

    const int w = tid >> 6, lane = tid & 63;
    const int d0 = lane * 8;

    #pragma unroll
    for (int e = 0; e < 2; ++e) {
        const int lrow = w * 2 + e;              // 0..7
        const int rowg = r0 + lrow;
        float vals[8];
        #pragma unroll
        for (int j = 0; j < 8; ++j) vals[j] = 0.f;
        #pragma unroll
        for (int k = 0; k < KCONV; ++k) {
            const float* src = qs[lrow + k];     // row (t-3+k)
            const float* cw = convw + k * DD + d0;
            #pragma unroll
            for (int j = 0; j < 8; ++j)
                vals[j] += src[d0 + j] * cw[j];
        }
        float ss = 0.f;
        #pragma unroll
        for (int j = 0; j < 8; ++j) ss += vals[j] * vals[j];
        #pragma unroll
        for (int off = 32; off > 0; off >>= 1)
            ss += __shfl_xor(ss, off);
        float inv = 1.f / fmaxf(sqrtf(ss), 1e-12f);
        unsigned short hv[8], lv[8];
        #pragma unroll
        for (int j = 0; j < 8; ++j) {
            float v = vals[j] * inv;
            unsigned short hi = f2bf(v);
            hv[j] = hi;
            lv[j] = f2bf(v - bf2f(hi));
        }
        size_t base = (size_t)rowg * DD + d0;
        *(ushort4*)(qh + base) = *(ushort4*)hv;
        *(ushort4*)(qh + base + 4) = *(ushort4*)(hv + 4);
        *(ushort4*)(ql + base) = *(ushort4*)lv;
        *(ushort4*)(ql + base + 4) = *(ushort4*)(lv + 4);
    }
}

// ---------------------------------------------------------------------------
// Flash sliding-window attention, MFMA, V^T staged from global.
// ---------------------------------------------------------------------------
__global__ __launch_bounds__(256, 2) void swa_flash_k(
    const unsigned short* __restrict__ qkvh, const unsigned short* __restrict__ qkvl,
    const unsigned short* __restrict__ vth, const unsigned short* __restrict__ vtl,
    unsigned short* __restrict__ oh, unsigned short* __restrict__ ol)
{
    // LDS: Kh 8192 | Kl 8192 | Vh 8192 | Vl 8192 | P 4x2304
    __shared__ short8v lds_v[41984 / 16];
    char* lds = (char*)lds_v;
    char* Kh_lds = lds;
    char* Kl_lds = lds + 8192;
    char* Vh_lds = lds + 16384;
    char* Vl_lds = lds + 24576;
    char* P_lds  = lds + 32768;

    const int tid = threadIdx.x;
    const int lane = tid & 63, w = tid >> 6;
    const int l15 = lane & 15, lg = lane >> 4;
    const int q0 = blockIdx.x * 64;
    const int h = blockIdx.y, b = blockIdx.z;
    const int rowbase = b * TT;

    const int qrow = rowbase + q0 + w * 16 + l15;
    short8v qhf[2], qlf[2];
    #pragma unroll
    for (int kh = 0; kh < 2; ++kh) {
        size_t off = (size_t)qrow * QKV_N + h * 64 + kh * 32 + lg * 8;
        qhf[kh] = *(const short8v*)(qkvh + off);
        qlf[kh] = *(const short8v*)(qkvl + off);
    }

    f32x4 o_acc[4];
    #pragma unroll
    for (int td = 0; td < 4; ++td) o_acc[td] = (f32x4){0.f, 0.f, 0.f, 0.f};
    float m_r[4], l_r[4];
    #pragma unroll
    for (int r = 0; r < 4; ++r) { m_r[r] = -1e30f; l_r[r] = 0.f; }

    char* Pw = P_lds + w * 2304;   // per-wave [16][72] bf16

    for (int kt = 0; kt < 5; ++kt) {
        const int kst = q0 - 256 + kt * 64;
        if (kst + 64 <= 0) continue;
        __syncthreads();
        #pragma unroll
        for (int it = 0; it < 2; ++it) {
            int lin = it * 256 + tid;
            int r = lin >> 3, seg = lin & 7;
            int colb = (seg * 16) ^ ((r & 7) << 4);
            size_t gb = ((size_t)(rowbase + kst + r) * QKV_N + 512 + h * 64) * 2 + colb;
            gload_lds16((const char*)qkvh + gb, Kh_lds + lin * 16);
            gload_lds16((const char*)qkvl + gb, Kl_lds + lin * 16);
        }
        #pragma unroll
        for (int it = 0; it < 2; ++it) {
            int lin = it * 256 + tid;
            int dd = lin >> 3, seg = lin & 7;
            int colb = (seg * 16) ^ ((dd & 7) << 4);
            size_t gb = ((size_t)(h * 64 + dd) * BT + rowbase + kst) * 2 + colb;
            gload_lds16((const char*)vth + gb, Vh_lds + lin * 16);
            gload_lds16((const char*)vtl + gb, Vl_lds + lin * 16);
        }
        __syncthreads();

        f32x4 s_fr[4];
        #pragma unroll
        for (int tj = 0; tj < 4; ++tj) s_fr[tj] = (f32x4){0.f, 0.f, 0.f, 0.f};
        #pragma unroll
        for (int tj = 0; tj < 4; ++tj) {
            int j = tj * 16 + l15;
            #pragma unroll
            for (int kh = 0; kh < 2; ++kh) {
                int colb = (kh * 64 + lg * 16) ^ ((j & 7) << 4);
                short8v kbh = *(const short8v*)(Kh_lds + j * 128 + colb);
                short8v kbl = *(const short8v*)(Kl_lds + j * 128 + colb);
                s_fr[tj] = __builtin_amdgcn_mfma_f32_16x16x32_bf16(qhf[kh], kbh, s_fr[tj], 0, 0, 0);
                s_fr[tj] = __builtin_amdgcn_mfma_f32_16x16x32_bf16(qhf[kh], kbl, s_fr[tj], 0, 0, 0);
                s_fr[tj] = __builtin_amdgcn_mfma_f32_16x16x32_bf16(qlf[kh], kbh, s_fr[tj], 0, 0, 0);
            }
        }
        #pragma unroll
        for (int tj = 0; tj < 4; ++tj) {
            int j = kst + tj * 16 + l15;
            #pragma unroll
            for (int r = 0; r < 4; ++r) {
                int i = q0 + w * 16 + lg * 4 + r;
                bool valid = (j <= i) && (i - j < WINN);
                s_fr[tj][r] = valid ? s_fr[tj][r] * 0.125f : -1e30f;
            }
        }
        float mx[4];
        #pragma unroll
        for (int r = 0; r < 4; ++r) {
            mx[r] = fmaxf(fmaxf(s_fr[0][r], s_fr[1][r]), fmaxf(s_fr[2][r], s_fr[3][r]));
            #pragma unroll
            for (int msk = 1; msk <= 8; msk <<= 1)
                mx[r] = fmaxf(mx[r], __shfl_xor(mx[r], msk));
            float mn = fmaxf(m_r[r], mx[r]);
            float sc = __expf(m_r[r] - mn);
            m_r[r] = mn;
            l_r[r] *= sc;
            #pragma unroll
            for (int td = 0; td < 4; ++td) o_acc[td][r] *= sc;
        }
        float rs[4] = {0.f, 0.f, 0.f, 0.f};
        #pragma unroll
        for (int tj = 0; tj < 4; ++tj) {
            #pragma unroll
            for (int r = 0; r < 4; ++r) {
                float p = __expf(s_fr[tj][r] - m_r[r]);
                rs[r] += p;
                ((unsigned short*)Pw)[(lg * 4 + r) * 72 + tj * 16 + l15] = f2bf(p);
            }
        }
        #pragma unroll
        for (int r = 0; r < 4; ++r) {
            #pragma unroll
            for (int msk = 1; msk <= 8; msk <<= 1)
                rs[r] += __shfl_xor(rs[r], msk);
            l_r[r] += rs[r];
        }
        short8v pa[2];
        #pragma unroll
        for (int jh = 0; jh < 2; ++jh)
            pa[jh] = *(const short8v*)(Pw + l15 * 144 + jh * 64 + lg * 16);
        #pragma unroll
        for (int td = 0; td < 4; ++td) {
            int drow = td * 16 + l15;
            #pragma unroll
            for (int jh = 0; jh < 2; ++jh) {
                int colb = (jh * 64 + lg * 16) ^ ((drow & 7) << 4);
                short8v vfh = *(const short8v*)(Vh_lds + drow * 128 + colb);
                short8v vfl = *(const short8v*)(Vl_lds + drow * 128 + colb);
                o_acc[td] = __builtin_amdgcn_mfma_f32_16x16x32_bf16(pa[jh], vfh, o_acc[td], 0, 0, 0);
                o_acc[td] = __builtin_amdgcn_mfma_f32_16x16x32_bf16(pa[jh], vfl, o_acc[td], 0, 0, 0);
            }
        }
    }

    #pragma unroll
    for (int r = 0; r < 4; ++r) {
        float inv = 1.f / l_r[r];
        int row = rowbase + q0 + w * 16 + lg * 4 + r;
        #pragma unroll
        for (int td = 0; td < 4; ++td) {
            float v = o_acc[td][r] * inv;
            size_t idx = (size_t)row * DD + h * 64 + td * 16 + l15;
            unsigned short hi = f2bf(v);
            oh[idx] = hi;
            ol[idx] = f2bf(v - bf2f(hi));
        }
    }
}

// ---------------------------------------------------------------------------
// Launch
// ---------------------------------------------------------------------------
extern "C" void kernel_launch(void* const* d_in, const int* in_sizes, int n_in,
                              void* d_out, int out_size, void* d_ws, size_t ws_size,
                              hipStream_t stream)
{
    const float* x       = (const float*)d_in[0];
    const float* meta    = (const float*)d_in[1];
    const float* qp_w    = (const float*)d_in[2];
    const float* qp_b    = (const float*)d_in[3];
    const float* qp_conv = (const float*)d_in[4];
    const float* w_in    = (const float*)d_in[5];
    const float* b_in    = (const float*)d_in[6];
    const float* w_hid   = (const float*)d_in[7];
    const float* b_hid   = (const float*)d_in[8];
    const float* w_out   = (const float*)d_in[9];
    const float* b_out   = (const float*)d_in[10];
    const float* wq      = (const float*)d_in[11];
    const float* bq      = (const float*)d_in[12];
    const float* wk      = (const float*)d_in[13];
    const float* bk      = (const float*)d_in[14];
    const float* wv      = (const float*)d_in[15];
    const float* bv      = (const float*)d_in[16];
    const float* wo      = (const float*)d_in[17];
    const float* bo      = (const float*)d_in[18];
    float* out = (float*)d_out;

    typedef unsigned short us;
    char* p = (char*)d_ws;
    auto alloc = [&](size_t n) { char* r = p; p += (n + 255) & ~(size_t)255; return r; };

    us* wqp_h   = (us*)alloc(512 * 512 * 2);   us* wqp_l   = (us*)alloc(512 * 512 * 2);
    us* win_h   = (us*)alloc(512 * 1024 * 2);  us* win_l   = (us*)alloc(512 * 1024 * 2);
    us* whid0_h = (us*)alloc(1024 * 1024 * 2); us* whid0_l = (us*)alloc(1024 * 1024 * 2);
    us* whid1_h = (us*)alloc(1024 * 1024 * 2); us* whid1_l = (us*)alloc(1024 * 1024 * 2);
    us* wout_h  = (us*)alloc(1024 * 512 * 2);  us* wout_l  = (us*)alloc(1024 * 512 * 2);
    us* wqkv_h  = (us*)alloc((size_t)QKV_N * 512 * 2);
    us* wqkv_l  = (us*)alloc((size_t)QKV_N * 512 * 2);
    us* wo_h    = (us*)alloc(512 * 512 * 2);   us* wo_l    = (us*)alloc(512 * 512 * 2);
    float* bqkv = (float*)alloc(QKV_N * 4);

    const size_t HALF = (size_t)BT * 512 * 2;   // 4.3 MB
    char* RA = alloc(2 * HALF);   // xm hi/lo  -> later ob hi/lo
    char* RB = alloc(2 * HALF);   // qlin fp32
    char* RC = alloc(2 * HALF);   // qn hi/lo -> r hi/lo
    char* RD = alloc(6 * HALF);   // ha hi/lo -> hc hi/lo -> qkv hi/lo (q,k only)
    char* RE = alloc(4 * HALF);   // hb hi/lo -> vt hi/lo ([512][BT] each)

    us* xm_h = (us*)RA;   us* xm_l = (us*)(RA + HALF);
    float* qlin = (float*)RB;
    us* qn_h = (us*)RC;   us* qn_l = (us*)(RC + HALF);
    us* ha_h = (us*)RD;   us* ha_l = (us*)(RD + 2 * HALF);
    us* hb_h = (us*)RE;   us* hb_l = (us*)(RE + 2 * HALF);
    us* hc_h = ha_h;      us* hc_l = ha_l;
    us* r_h  = qn_h;      us* r_l  = qn_l;
    us* qkv_h = (us*)RD;  us* qkv_l = (us*)(RD + 3 * HALF);
    us* vt_h  = (us*)RE;  us* vt_l  = (us*)(RE + HALF);
    us* ob_h = (us*)RA;   us* ob_l = (us*)(RA + HALF);

    // --- merged prep: wsplit (1088) + build_xm (2112) + bias (6) ---
    WJobs jb;
    const float* Ws[9]   = {qp_w, w_in, w_hid, w_hid + (size_t)1024 * 1024, w_out,
                            wq, wk, wv, wo};
    us* Whs[9] = {wqp_h, win_h, whid0_h, whid1_h, wout_h,
                  wqkv_h, wqkv_h + 512 * 512, wqkv_h + 2 * 512 * 512, wo_h};
    us* Wls[9] = {wqp_l, win_l, whid0_l, whid1_l, wout_l,
                  wqkv_l, wqkv_l + 512 * 512, wqkv_l + 2 * 512 * 512, wo_l};
    int Ks[9] = {512, 512, 1024, 1024, 1024, 512, 512, 512, 512};
    int Ns[9] = {512, 1024, 1024, 1024, 512, 512, 512, 512, 512};
    int acc_t = 0;
    for (int j = 0; j < 9; ++j) {
        jb.W[j] = Ws[j]; jb.Wh[j] = Whs[j]; jb.Wl[j] = Wls[j];
        jb.K[j] = Ks[j]; jb.N[j] = Ns[j];
        jb.base[j] = acc_t;
        acc_t += (Ks[j] / 64) * (Ns[j] / 64);
    }
    jb.base[9] = acc_t;    // 1088
    prep_all_k<<<3206, 256, 0, stream>>>(jb, x, meta, xm_h, xm_l, bq, bk, bv, bqkv);

    // --- pipeline (R7 best config) ---
    // qlin = xm @ qp_w + b (fp32 out): N=512, BN=64, grid 528
    gemm_mfma_k<64, 8, 0, false><<<528, 256, 0, stream>>>(
        xm_h, xm_l, wqp_h, wqp_l, qp_b, nullptr, nullptr, qlin, nullptr, nullptr, nullptr, nullptr, 512, 512);
    conv_norm8_k<<<BT / 8, 256, 0, stream>>>(qlin, qp_conv, qn_h, qn_l);
    // ha = silu(qn @ w_in + b_in): N=1024, BN=128, grid 528
    gemm_mfma_k<128, 8, 1, false><<<528, 256, 0, stream>>>(
        qn_h, qn_l, win_h, win_l, b_in, nullptr, nullptr, nullptr, ha_h, ha_l, nullptr, nullptr, 512, 1024);
    gemm_mfma_k<128, 8, 2, false><<<528, 256, 0, stream>>>(
        ha_h, ha_l, whid0_h, whid0_l, b_hid, ha_h, ha_l, nullptr, hb_h, hb_l, nullptr, nullptr, 1024, 1024);
    gemm_mfma_k<128, 8, 2, false><<<528, 256, 0, stream>>>(
        hb_h, hb_l, whid1_h, whid1_l, b_hid + HH, hb_h, hb_l, nullptr, hc_h, hc_l, nullptr, nullptr, 1024, 1024);
    // r = silu(hc @ w_out + b_out): N=512, BN=64, grid 528
    gemm_mfma_k<64, 8, 1, false><<<528, 256, 0, stream>>>(
        hc_h, hc_l, wout_h, wout_l, b_out, nullptr, nullptr, nullptr, r_h, r_l, nullptr, nullptr, 1024, 512);
    // fused q/k/v projection: N=1536, BN=128, grid 792
    gemm_mfma_k<128, 12, 4, false><<<792, 256, 0, stream>>>(
        r_h, r_l, wqkv_h, wqkv_l, bqkv, nullptr, nullptr, nullptr, qkv_h, qkv_l, vt_h, vt_l, 512, QKV_N);
    // flash sliding-window attention
    swa_flash_k<<<dim3(TT / 64, NHH, BB), 256, 0, stream>>>(qkv_h, qkv_l, vt_h, vt_l, ob_h, ob_l);
    // out = (ob @ wo + bo)[t >= M]: N=512, BN=64, grid 528
    gemm_mfma_k<64, 8, 0, true><<<528, 256, 0, stream>>>(
        ob_h, ob_l, wo_h, wo_l, bo, nullptr, nullptr, out, nullptr, nullptr, nullptr, nullptr, 512, 512);
}

// Round 13
// 194.403 us; speedup vs baseline: 2.4689x; 1.2785x over previous
//
#include <hip/hip_runtime.h>
#include <math.h>
#include <stdint.h>

#define BB 2
#define SS 2048
#define DD 512
#define HH 1024
#define MMETA 64
#define KCONV 4
#define NHH 8
#define DHH 64
#define WINN 256
#define TT (MMETA + SS)     // 2112
#define BT (BB * TT)        // 4224
#define QKV_N 1536

typedef __attribute__((ext_vector_type(8))) short short8v;   // 8 bf16 = 4 VGPR
typedef __attribute__((ext_vector_type(4))) float f32x4;

__device__ __forceinline__ unsigned short f2bf(float f) {
    union { float f; unsigned u; } c; c.f = f;
    unsigned u = c.u;
    unsigned r = (u + 0x7fffu + ((u >> 16) & 1u)) >> 16;   // RNE
    return (unsigned short)r;
}
__device__ __forceinline__ float bf2f(unsigned short h) {
    union { unsigned u; float f; } c; c.u = ((unsigned)h) << 16;
    return c.f;
}

__device__ __forceinline__ void gload_lds16(const void* g, void* l) {
    __builtin_amdgcn_global_load_lds(
        (const __attribute__((address_space(1))) unsigned int*)g,
        (__attribute__((address_space(3))) unsigned int*)l, 16, 0, 0);
}

// counted vmcnt wait (T4)
template<int N>
__device__ __forceinline__ void vm_wait() {
    if constexpr (N == 0)      asm volatile("s_waitcnt vmcnt(0)" ::: "memory");
    else if constexpr (N == 3) asm volatile("s_waitcnt vmcnt(3)" ::: "memory");
    else if constexpr (N == 4) asm volatile("s_waitcnt vmcnt(4)" ::: "memory");
    else static_assert(N == 0, "unsupported vmcnt");
}

// ---------------------------------------------------------------------------
// merged prep: 9x weight transpose (single bf16) | build_xm | bias concat
//   blocks [0,1088): wsplit; [1088,3200): build_xm; [3200,3206): bias
// ---------------------------------------------------------------------------
struct WJobs {
    const float* W[9];
    unsigned short* Wh[9];
    int K[9];
    int N[9];
    int base[10];
};

__global__ __launch_bounds__(256) void prep_all_k(
    WJobs jb,
    const float* __restrict__ x, const float* __restrict__ meta,
    unsigned short* __restrict__ xh, unsigned short* __restrict__ xl,
    const float* __restrict__ bq, const float* __restrict__ bk,
    const float* __restrict__ bv, float* __restrict__ bqkv)
{
    __shared__ float tile[64][65];
    const int bid = blockIdx.x;
    const int tid = threadIdx.x;

    if (bid < 1088) {
        int j = 0;
        while (bid >= jb.base[j + 1]) ++j;
        const int local = bid - jb.base[j];
        const int K = jb.K[j], N = jb.N[j];
        const int nx = N >> 6;
        const int k0 = (local / nx) * 64, n0 = (local % nx) * 64;
        const float* W = jb.W[j];
        unsigned short* Wh = jb.Wh[j];
        #pragma unroll
        for (int i = 0; i < 16; ++i) {
            int lin = i * 256 + tid;
            int kr = lin >> 6, nc = lin & 63;
            tile[kr][nc] = W[(size_t)(k0 + kr) * N + n0 + nc];
        }
        __syncthreads();
        #pragma unroll
        for (int i = 0; i < 16; ++i) {
            int lin = i * 256 + tid;
            int nr = lin >> 6, kc = lin & 63;
            Wh[(size_t)(n0 + nr) * K + k0 + kc] = f2bf(tile[kc][nr]);
        }
    } else if (bid < 3200) {
        int idx = (bid - 1088) * 256 + tid;   // float4 index over BT*128
        int row = idx >> 7, c4 = idx & 127;
        int b = row >= TT;
        int t = row - b * TT;
        float4 v = (t < MMETA) ? ((const float4*)(meta + (size_t)t * DD))[c4]
                               : ((const float4*)(x + ((size_t)b * SS + (t - MMETA)) * DD))[c4];
        ushort4 h, lo;
        h.x = f2bf(v.x); lo.x = f2bf(v.x - bf2f(h.x));
        h.y = f2bf(v.y); lo.y = f2bf(v.y - bf2f(h.y));
        h.z = f2bf(v.z); lo.z = f2bf(v.z - bf2f(h.z));
        h.w = f2bf(v.w); lo.w = f2bf(v.w - bf2f(h.w));
        ((ushort4*)xh)[idx] = h;
        ((ushort4*)xl)[idx] = lo;
    } else {
        int i = (bid - 3200) * 256 + tid;
        if (i < QKV_N) {
            float v;
            if (i < 512) v = bq[i];
            else if (i < 1024) v = bk[i - 512];
            else v = bv[i - 1024];
            bqkv[i] = v;
        }
    }
}

// ---------------------------------------------------------------------------
// bf16x2 MFMA GEMM: activations hi/lo, weights single bf16.
//   D = ah*w + al*w  (2 MFMA per fragment pair; exact-split A, rounded W)
//   BM=64; BN in {64,128}; counted-vmcnt double-buffer (T4); grid 66*GN.
//   EPI: 0 bias->fp32; 1 silu->hi/lo; 2 res+silu->hi/lo;
//        4 bias->hi/lo for cols<1024, transposed vt write for cols>=1024
// ---------------------------------------------------------------------------
template<int BN, int GN, int EPI, bool DROPMETA>
__global__ __launch_bounds__(256, 3) void gemm_mfma_k(
    const unsigned short* __restrict__ Ah, const unsigned short* __restrict__ Al,
    const unsigned short* __restrict__ Wh,
    const float* __restrict__ bias,
    const unsigned short* __restrict__ resh, const unsigned short* __restrict__ resl,
    float* __restrict__ outf, unsigned short* __restrict__ outh,
    unsigned short* __restrict__ outl,
    unsigned short* __restrict__ vth, unsigned short* __restrict__ vtl,
    int K, int N)
{
    constexpr int BM = 64;
    constexpr int MF = 2;              // wave covers 32 rows
    constexpr int NF = BN / 32;        // wave covers BN/2 cols
    constexpr int ABYTES = BM * 64;    // 4 KB per A half
    constexpr int BBYTES = BN * 64;    // single B plane
    constexpr int BUFB = 2 * ABYTES + BBYTES;
    constexpr int LOADS = 2 + BN / 64; // per-thread loads per stage
    __shared__ short8v smem_v[(2 * BUFB) / 16];
    char* smem = (char*)smem_v;

    // XCD-chunk swizzle (bijective since NWG % 8 == 0)
    constexpr int NWG = 66 * GN;
    const int orig = blockIdx.x;
    const int swz = (orig & 7) * (NWG >> 3) + (orig >> 3);
    const int row0 = (swz / GN) * BM;
    const int n0 = (swz % GN) * BN;

    const int tid = threadIdx.x;
    const int l = tid & 63, wid = tid >> 6;
    const int wm = wid >> 1, wn = wid & 1;
    const int lr = l & 15, lg = l >> 4;

    const char* Ahg0 = (const char*)Ah + (size_t)row0 * K * 2;
    const char* Alg0 = (const char*)Al + (size_t)row0 * K * 2;
    const char* Whg  = (const char*)Wh + (size_t)n0 * K * 2;

    // conflict-free swizzle: sigma(r) = (r>>1)&3 over the 4 16B segs of a row
    int a_off[MF], b_off[NF];
    #pragma unroll
    for (int mf = 0; mf < MF; ++mf) {
        int r = wm * 32 + mf * 16 + lr;
        a_off[mf] = r * 64 + ((lg * 16) ^ (((r >> 1) & 3) << 4));
    }
    #pragma unroll
    for (int nf = 0; nf < NF; ++nf) {
        int r = wn * (BN / 2) + nf * 16 + lr;
        b_off[nf] = r * 64 + ((lg * 16) ^ (((r >> 1) & 3) << 4));
    }

    f32x4 acc[MF][NF];
    #pragma unroll
    for (int mf = 0; mf < MF; ++mf)
        #pragma unroll
        for (int nf = 0; nf < NF; ++nf) acc[mf][nf] = (f32x4){0.f, 0.f, 0.f, 0.f};

    const int NT = K / 32;

    auto stage = [&](int buf, int t) {
        char* lb = smem + buf * BUFB;
        const size_t kb = (size_t)t * 64;
        {
            int off = tid * 16;
            int row = off >> 6;
            int sc = (off & 63) ^ (((row >> 1) & 3) << 4);
            size_t gb = (size_t)row * (K * 2) + kb + sc;
            gload_lds16(Ahg0 + gb, lb + off);
            gload_lds16(Alg0 + gb, lb + ABYTES + off);
        }
        #pragma unroll
        for (int it = 0; it < BBYTES / 4096; ++it) {
            int off = (it * 256 + tid) * 16;
            int row = off >> 6;
            int sc = (off & 63) ^ (((row >> 1) & 3) << 4);
            size_t gb = (size_t)row * (K * 2) + kb + sc;
            gload_lds16(Whg + gb, lb + 2 * ABYTES + off);
        }
    };

    stage(0, 0);

    int cur = 0;
    for (int t = 0; t < NT; ++t) {
        if (t + 1 < NT) {
            stage(cur ^ 1, t + 1);
            vm_wait<LOADS>();        // wait only tile t's loads; t+1 stays in flight
        } else {
            vm_wait<0>();
        }
        __builtin_amdgcn_s_barrier();
        __builtin_amdgcn_sched_barrier(0);

        char* lb = smem + cur * BUFB;
        short8v ah[MF], al[MF], bh[NF];
        #pragma unroll
        for (int mf = 0; mf < MF; ++mf) {
            ah[mf] = *(const short8v*)(lb + a_off[mf]);
            al[mf] = *(const short8v*)(lb + ABYTES + a_off[mf]);
        }
        #pragma unroll
        for (int nf = 0; nf < NF; ++nf)
            bh[nf] = *(const short8v*)(lb + 2 * ABYTES + b_off[nf]);
        __builtin_amdgcn_s_setprio(1);
        #pragma unroll
        for (int mf = 0; mf < MF; ++mf)
            #pragma unroll
            for (int nf = 0; nf < NF; ++nf) {
                acc[mf][nf] = __builtin_amdgcn_mfma_f32_16x16x32_bf16(ah[mf], bh[nf], acc[mf][nf], 0, 0, 0);
                acc[mf][nf] = __builtin_amdgcn_mfma_f32_16x16x32_bf16(al[mf], bh[nf], acc[mf][nf], 0, 0, 0);
            }
        __builtin_amdgcn_s_setprio(0);
        __builtin_amdgcn_s_barrier();    // all reads of buf[cur] done before overwrite
        cur ^= 1;
    }

    // epilogue: C/D layout col = lane&15, row = (lane>>4)*4 + reg
    #pragma unroll
    for (int mf = 0; mf < MF; ++mf) {
        #pragma unroll
        for (int nf = 0; nf < NF; ++nf) {
            int col = n0 + wn * (BN / 2) + nf * 16 + lr;
            float bv = bias[col];
            if (EPI == 4 && col >= 1024) {
                unsigned short hv[4], lv[4];
                #pragma unroll
                for (int j = 0; j < 4; ++j) {
                    float v = acc[mf][nf][j] + bv;
                    unsigned short hi = f2bf(v);
                    hv[j] = hi; lv[j] = f2bf(v - bf2f(hi));
                }
                int dg = col - 1024;
                size_t tok = (size_t)row0 + wm * 32 + mf * 16 + lg * 4;
                *(ushort4*)(vth + (size_t)dg * BT + tok) = *(ushort4*)hv;
                *(ushort4*)(vtl + (size_t)dg * BT + tok) = *(ushort4*)lv;
            } else {
                #pragma unroll
                for (int j = 0; j < 4; ++j) {
                    int row = row0 + wm * 32 + mf * 16 + lg * 4 + j;
                    float v = acc[mf][nf][j] + bv;
                    if (EPI == 1 || EPI == 2) v = v / (1.f + __expf(-v));
                    size_t idx = (size_t)row * N + col;
                    if (EPI == 2) v += bf2f(resh[idx]) + bf2f(resl[idx]);
                    if (EPI == 0) {
                        if (DROPMETA) {
                            int b = row >= TT;
                            int t2 = row - b * TT;
                            if (t2 >= MMETA)
                                outf[((size_t)b * SS + (t2 - MMETA)) * N + col] = v;
                        } else {
                            outf[idx] = v;
                        }
                    } else {
                        unsigned short hi = f2bf(v);
                        outh[idx] = hi;
                        outl[idx] = f2bf(v - bf2f(hi));
                    }
                }
            }
        }
    }
}

// ---------------------------------------------------------------------------
// causal depthwise conv (K=4) + L2 normalize; 8 rows/block with LDS row reuse.
// ---------------------------------------------------------------------------
__global__ __launch_bounds__(256) void conv_norm8_k(
    const float* __restrict__ qlin, const float* __restrict__ convw,
    unsigned short* __restrict__ qh, unsigned short* __restrict__ ql)
{
    __shared__ float qs[11][512];
    const int tid = threadIdx.x;
    const int r0 = blockIdx.x * 8;               // 2112 % 8 == 0: no batch straddle
    const int b = r0 >= TT;
    const int bstart = b * TT;

    const float4* ql4 = (const float4*)qlin;
    for (int i = tid; i < 11 * 128; i += 256) {
        int lrow = i >> 7, c4 = i & 127;
        int grow = r0 - 3 + lrow;
        float4 v = (grow >= bstart) ? ql4[(size_t)grow * 128 + c4]
                                    : (float4){0.f, 0.f, 0.f, 0.f};
        ((float4*)qs[lrow])[c4] = v;
    }
    __syncthreads();

    const int w = tid >> 6, lane = tid & 63;
    const int d0 = lane * 8;

    #pragma unroll
    for (int e = 0; e < 2; ++e) {
        const int lrow = w * 2 + e;              // 0..7
        const int rowg = r0 + lrow;
        float vals[8];
        #pragma unroll
        for (int j = 0; j < 8; ++j) vals[j] = 0.f;
        #pragma unroll
        for (int k = 0; k < KCONV; ++k) {
            const float* src = qs[lrow + k];
            const float* cw = convw + k * DD + d0;
            #pragma unroll
            for (int j = 0; j < 8; ++j)
                vals[j] += src[d0 + j] * cw[j];
        }
        float ss = 0.f;
        #pragma unroll
        for (int j = 0; j < 8; ++j) ss += vals[j] * vals[j];
        #pragma unroll
        for (int off = 32; off > 0; off >>= 1)
            ss += __shfl_xor(ss, off);
        float inv = 1.f / fmaxf(sqrtf(ss), 1e-12f);
        unsigned short hv[8], lv[8];
        #pragma unroll
        for (int j = 0; j < 8; ++j) {
            float v = vals[j] * inv;
            unsigned short hi = f2bf(v);
            hv[j] = hi;
            lv[j] = f2bf(v - bf2f(hi));
        }
        size_t base = (size_t)rowg * DD + d0;
        *(ushort4*)(qh + base) = *(ushort4*)hv;
        *(ushort4*)(qh + base + 4) = *(ushort4*)(hv + 4);
        *(ushort4*)(ql + base) = *(ushort4*)lv;
        *(ushort4*)(ql + base + 4) = *(ushort4*)(lv + 4);
    }
}

// ---------------------------------------------------------------------------
// Flash sliding-window attention, MFMA, V^T staged from global. (unchanged)
// ---------------------------------------------------------------------------
__global__ __launch_bounds__(256, 2) void swa_flash_k(
    const unsigned short* __restrict__ qkvh, const unsigned short* __restrict__ qkvl,
    const unsigned short* __restrict__ vth, const unsigned short* __restrict__ vtl,
    unsigned short* __restrict__ oh, unsigned short* __restrict__ ol)
{
    // LDS: Kh 8192 | Kl 8192 | Vh 8192 | Vl 8192 | P 4x2304
    __shared__ short8v lds_v[41984 / 16];
    char* lds = (char*)lds_v;
    char* Kh_lds = lds;
    char* Kl_lds = lds + 8192;
    char* Vh_lds = lds + 16384;
    char* Vl_lds = lds + 24576;
    char* P_lds  = lds + 32768;

    const int tid = threadIdx.x;
    const int lane = tid & 63, w = tid >> 6;
    const int l15 = lane & 15, lg = lane >> 4;
    const int q0 = blockIdx.x * 64;
    const int h = blockIdx.y, b = blockIdx.z;
    const int rowbase = b * TT;

    const int qrow = rowbase + q0 + w * 16 + l15;
    short8v qhf[2], qlf[2];
    #pragma unroll
    for (int kh = 0; kh < 2; ++kh) {
        size_t off = (size_t)qrow * QKV_N + h * 64 + kh * 32 + lg * 8;
        qhf[kh] = *(const short8v*)(qkvh + off);
        qlf[kh] = *(const short8v*)(qkvl + off);
    }

    f32x4 o_acc[4];
    #pragma unroll
    for (int td = 0; td < 4; ++td) o_acc[td] = (f32x4){0.f, 0.f, 0.f, 0.f};
    float m_r[4], l_r[4];
    #pragma unroll
    for (int r = 0; r < 4; ++r) { m_r[r] = -1e30f; l_r[r] = 0.f; }

    char* Pw = P_lds + w * 2304;   // per-wave [16][72] bf16

    for (int kt = 0; kt < 5; ++kt) {
        const int kst = q0 - 256 + kt * 64;
        if (kst + 64 <= 0) continue;
        __syncthreads();
        #pragma unroll
        for (int it = 0; it < 2; ++it) {
            int lin = it * 256 + tid;
            int r = lin >> 3, seg = lin & 7;
            int colb = (seg * 16) ^ ((r & 7) << 4);
            size_t gb = ((size_t)(rowbase + kst + r) * QKV_N + 512 + h * 64) * 2 + colb;
            gload_lds16((const char*)qkvh + gb, Kh_lds + lin * 16);
            gload_lds16((const char*)qkvl + gb, Kl_lds + lin * 16);
        }
        #pragma unroll
        for (int it = 0; it < 2; ++it) {
            int lin = it * 256 + tid;
            int dd = lin >> 3, seg = lin & 7;
            int colb = (seg * 16) ^ ((dd & 7) << 4);
            size_t gb = ((size_t)(h * 64 + dd) * BT + rowbase + kst) * 2 + colb;
            gload_lds16((const char*)vth + gb, Vh_lds + lin * 16);
            gload_lds16((const char*)vtl + gb, Vl_lds + lin * 16);
        }
        __syncthreads();

        f32x4 s_fr[4];
        #pragma unroll
        for (int tj = 0; tj < 4; ++tj) s_fr[tj] = (f32x4){0.f, 0.f, 0.f, 0.f};
        #pragma unroll
        for (int tj = 0; tj < 4; ++tj) {
            int j = tj * 16 + l15;
            #pragma unroll
            for (int kh = 0; kh < 2; ++kh) {
                int colb = (kh * 64 + lg * 16) ^ ((j & 7) << 4);
                short8v kbh = *(const short8v*)(Kh_lds + j * 128 + colb);
                short8v kbl = *(const short8v*)(Kl_lds + j * 128 + colb);
                s_fr[tj] = __builtin_amdgcn_mfma_f32_16x16x32_bf16(qhf[kh], kbh, s_fr[tj], 0, 0, 0);
                s_fr[tj] = __builtin_amdgcn_mfma_f32_16x16x32_bf16(qhf[kh], kbl, s_fr[tj], 0, 0, 0);
                s_fr[tj] = __builtin_amdgcn_mfma_f32_16x16x32_bf16(qlf[kh], kbh, s_fr[tj], 0, 0, 0);
            }
        }
        #pragma unroll
        for (int tj = 0; tj < 4; ++tj) {
            int j = kst + tj * 16 + l15;
            #pragma unroll
            for (int r = 0; r < 4; ++r) {
                int i = q0 + w * 16 + lg * 4 + r;
                bool valid = (j <= i) && (i - j < WINN);
                s_fr[tj][r] = valid ? s_fr[tj][r] * 0.125f : -1e30f;
            }
        }
        float mx[4];
        #pragma unroll
        for (int r = 0; r < 4; ++r) {
            mx[r] = fmaxf(fmaxf(s_fr[0][r], s_fr[1][r]), fmaxf(s_fr[2][r], s_fr[3][r]));
            #pragma unroll
            for (int msk = 1; msk <= 8; msk <<= 1)
                mx[r] = fmaxf(mx[r], __shfl_xor(mx[r], msk));
            float mn = fmaxf(m_r[r], mx[r]);
            float sc = __expf(m_r[r] - mn);
            m_r[r] = mn;
            l_r[r] *= sc;
            #pragma unroll
            for (int td = 0; td < 4; ++td) o_acc[td][r] *= sc;
        }
        float rs[4] = {0.f, 0.f, 0.f, 0.f};
        #pragma unroll
        for (int tj = 0; tj < 4; ++tj) {
            #pragma unroll
            for (int r = 0; r < 4; ++r) {
                float p = __expf(s_fr[tj][r] - m_r[r]);
                rs[r] += p;
                ((unsigned short*)Pw)[(lg * 4 + r) * 72 + tj * 16 + l15] = f2bf(p);
            }
        }
        #pragma unroll
        for (int r = 0; r < 4; ++r) {
            #pragma unroll
            for (int msk = 1; msk <= 8; msk <<= 1)
                rs[r] += __shfl_xor(rs[r], msk);
            l_r[r] += rs[r];
        }
        short8v pa[2];
        #pragma unroll
        for (int jh = 0; jh < 2; ++jh)
            pa[jh] = *(const short8v*)(Pw + l15 * 144 + jh * 64 + lg * 16);
        #pragma unroll
        for (int td = 0; td < 4; ++td) {
            int drow = td * 16 + l15;
            #pragma unroll
            for (int jh = 0; jh < 2; ++jh) {
                int colb = (jh * 64 + lg * 16) ^ ((drow & 7) << 4);
                short8v vfh = *(const short8v*)(Vh_lds + drow * 128 + colb);
                short8v vfl = *(const short8v*)(Vl_lds + drow * 128 + colb);
                o_acc[td] = __builtin_amdgcn_mfma_f32_16x16x32_bf16(pa[jh], vfh, o_acc[td], 0, 0, 0);
                o_acc[td] = __builtin_amdgcn_mfma_f32_16x16x32_bf16(pa[jh], vfl, o_acc[td], 0, 0, 0);
            }
        }
    }

    #pragma unroll
    for (int r = 0; r < 4; ++r) {
        float inv = 1.f / l_r[r];
        int row = rowbase + q0 + w * 16 + lg * 4 + r;
        #pragma unroll
        for (int td = 0; td < 4; ++td) {
            float v = o_acc[td][r] * inv;
            size_t idx = (size_t)row * DD + h * 64 + td * 16 + l15;
            unsigned short hi = f2bf(v);
            oh[idx] = hi;
            ol[idx] = f2bf(v - bf2f(hi));
        }
    }
}

// ---------------------------------------------------------------------------
// Launch
// ---------------------------------------------------------------------------
extern "C" void kernel_launch(void* const* d_in, const int* in_sizes, int n_in,
                              void* d_out, int out_size, void* d_ws, size_t ws_size,
                              hipStream_t stream)
{
    const float* x       = (const float*)d_in[0];
    const float* meta    = (const float*)d_in[1];
    const float* qp_w    = (const float*)d_in[2];
    const float* qp_b    = (const float*)d_in[3];
    const float* qp_conv = (const float*)d_in[4];
    const float* w_in    = (const float*)d_in[5];
    const float* b_in    = (const float*)d_in[6];
    const float* w_hid   = (const float*)d_in[7];
    const float* b_hid   = (const float*)d_in[8];
    const float* w_out   = (const float*)d_in[9];
    const float* b_out   = (const float*)d_in[10];
    const float* wq      = (const float*)d_in[11];
    const float* bq      = (const float*)d_in[12];
    const float* wk      = (const float*)d_in[13];
    const float* bk      = (const float*)d_in[14];
    const float* wv      = (const float*)d_in[15];
    const float* bv      = (const float*)d_in[16];
    const float* wo      = (const float*)d_in[17];
    const float* bo      = (const float*)d_in[18];
    float* out = (float*)d_out;

    typedef unsigned short us;
    char* p = (char*)d_ws;
    auto alloc = [&](size_t n) { char* r = p; p += (n + 255) & ~(size_t)255; return r; };

    // weights: single bf16, transposed [N][K]
    us* wqp_h   = (us*)alloc(512 * 512 * 2);
    us* win_h   = (us*)alloc(512 * 1024 * 2);
    us* whid0_h = (us*)alloc(1024 * 1024 * 2);
    us* whid1_h = (us*)alloc(1024 * 1024 * 2);
    us* wout_h  = (us*)alloc(1024 * 512 * 2);
    us* wqkv_h  = (us*)alloc((size_t)QKV_N * 512 * 2);
    us* wo_h    = (us*)alloc(512 * 512 * 2);
    float* bqkv = (float*)alloc(QKV_N * 4);

    const size_t HALF = (size_t)BT * 512 * 2;   // 4.3 MB
    char* RA = alloc(2 * HALF);   // xm hi/lo  -> later ob hi/lo
    char* RB = alloc(2 * HALF);   // qlin fp32
    char* RC = alloc(2 * HALF);   // qn hi/lo -> r hi/lo
    char* RD = alloc(6 * HALF);   // ha hi/lo -> hc hi/lo -> qkv hi/lo (q,k only)
    char* RE = alloc(4 * HALF);   // hb hi/lo -> vt hi/lo ([512][BT] each)

    us* xm_h = (us*)RA;   us* xm_l = (us*)(RA + HALF);
    float* qlin = (float*)RB;
    us* qn_h = (us*)RC;   us* qn_l = (us*)(RC + HALF);
    us* ha_h = (us*)RD;   us* ha_l = (us*)(RD + 2 * HALF);
    us* hb_h = (us*)RE;   us* hb_l = (us*)(RE + 2 * HALF);
    us* hc_h = ha_h;      us* hc_l = ha_l;
    us* r_h  = qn_h;      us* r_l  = qn_l;
    us* qkv_h = (us*)RD;  us* qkv_l = (us*)(RD + 3 * HALF);
    us* vt_h  = (us*)RE;  us* vt_l  = (us*)(RE + HALF);
    us* ob_h = (us*)RA;   us* ob_l = (us*)(RA + HALF);

    // --- merged prep: wsplit (1088) + build_xm (2112) + bias (6) ---
    WJobs jb;
    const float* Ws[9]   = {qp_w, w_in, w_hid, w_hid + (size_t)1024 * 1024, w_out,
                            wq, wk, wv, wo};
    us* Whs[9] = {wqp_h, win_h, whid0_h, whid1_h, wout_h,
                  wqkv_h, wqkv_h + 512 * 512, wqkv_h + 2 * 512 * 512, wo_h};
    int Ks[9] = {512, 512, 1024, 1024, 1024, 512, 512, 512, 512};
    int Ns[9] = {512, 1024, 1024, 1024, 512, 512, 512, 512, 512};
    int acc_t = 0;
    for (int j = 0; j < 9; ++j) {
        jb.W[j] = Ws[j]; jb.Wh[j] = Whs[j];
        jb.K[j] = Ks[j]; jb.N[j] = Ns[j];
        jb.base[j] = acc_t;
        acc_t += (Ks[j] / 64) * (Ns[j] / 64);
    }
    jb.base[9] = acc_t;    // 1088
    prep_all_k<<<3206, 256, 0, stream>>>(jb, x, meta, xm_h, xm_l, bq, bk, bv, bqkv);

    // --- pipeline (R7/R12 config, bf16x2) ---
    // qlin = xm @ qp_w + b (fp32 out): N=512, BN=64, grid 528
    gemm_mfma_k<64, 8, 0, false><<<528, 256, 0, stream>>>(
        xm_h, xm_l, wqp_h, qp_b, nullptr, nullptr, qlin, nullptr, nullptr, nullptr, nullptr, 512, 512);
    conv_norm8_k<<<BT / 8, 256, 0, stream>>>(qlin, qp_conv, qn_h, qn_l);
    // ha = silu(qn @ w_in + b_in): N=1024, BN=128, grid 528
    gemm_mfma_k<128, 8, 1, false><<<528, 256, 0, stream>>>(
        qn_h, qn_l, win_h, b_in, nullptr, nullptr, nullptr, ha_h, ha_l, nullptr, nullptr, 512, 1024);
    gemm_mfma_k<128, 8, 2, false><<<528, 256, 0, stream>>>(
        ha_h, ha_l, whid0_h, b_hid, ha_h, ha_l, nullptr, hb_h, hb_l, nullptr, nullptr, 1024, 1024);
    gemm_mfma_k<128, 8, 2, false><<<528, 256, 0, stream>>>(
        hb_h, hb_l, whid1_h, b_hid + HH, hb_h, hb_l, nullptr, hc_h, hc_l, nullptr, nullptr, 1024, 1024);
    // r = silu(hc @ w_out + b_out): N=512, BN=64, grid 528
    gemm_mfma_k<64, 8, 1, false><<<528, 256, 0, stream>>>(
        hc_h, hc_l, wout_h, b_out, nullptr, nullptr, nullptr, r_h, r_l, nullptr, nullptr, 1024, 512);
    // fused q/k/v projection: N=1536, BN=128, grid 792
    gemm_mfma_k<128, 12, 4, false><<<792, 256, 0, stream>>>(
        r_h, r_l, wqkv_h, bqkv, nullptr, nullptr, nullptr, qkv_h, qkv_l, vt_h, vt_l, 512, QKV_N);
    // flash sliding-window attention
    swa_flash_k<<<dim3(TT / 64, NHH, BB), 256, 0, stream>>>(qkv_h, qkv_l, vt_h, vt_l, ob_h, ob_l);
    // out = (ob @ wo + bo)[t >= M]: N=512, BN=64, grid 528
    gemm_mfma_k<64, 8, 0, true><<<528, 256, 0, stream>>>(
        ob_h, ob_l, wo_h, bo, nullptr, nullptr, out, nullptr, nullptr, nullptr, nullptr, 512, 512);
}

// Round 14
// 164.620 us; speedup vs baseline: 2.9156x; 1.1809x over previous
//
#include <hip/hip_runtime.h>
#include <math.h>
#include <stdint.h>

#define BB 2
#define SS 2048
#define DD 512
#define HH 1024
#define MMETA 64
#define KCONV 4
#define NHH 8
#define DHH 64
#define WINN 256
#define TT (MMETA + SS)     // 2112
#define BT (BB * TT)        // 4224
#define QKV_N 1536

typedef __attribute__((ext_vector_type(8))) short short8v;   // 8 bf16 = 4 VGPR
typedef __attribute__((ext_vector_type(4))) float f32x4;

__device__ __forceinline__ unsigned short f2bf(float f) {
    union { float f; unsigned u; } c; c.f = f;
    unsigned u = c.u;
    unsigned r = (u + 0x7fffu + ((u >> 16) & 1u)) >> 16;   // RNE
    return (unsigned short)r;
}
__device__ __forceinline__ float bf2f(unsigned short h) {
    union { unsigned u; float f; } c; c.u = ((unsigned)h) << 16;
    return c.f;
}

__device__ __forceinline__ void gload_lds16(const void* g, void* l) {
    __builtin_amdgcn_global_load_lds(
        (const __attribute__((address_space(1))) unsigned int*)g,
        (__attribute__((address_space(3))) unsigned int*)l, 16, 0, 0);
}

// counted vmcnt wait (T4)
template<int N>
__device__ __forceinline__ void vm_wait() {
    if constexpr (N == 0)      asm volatile("s_waitcnt vmcnt(0)" ::: "memory");
    else if constexpr (N == 2) asm volatile("s_waitcnt vmcnt(2)" ::: "memory");
    else if constexpr (N == 3) asm volatile("s_waitcnt vmcnt(3)" ::: "memory");
    else if constexpr (N == 4) asm volatile("s_waitcnt vmcnt(4)" ::: "memory");
    else static_assert(N == 0, "unsupported vmcnt");
}

// ---------------------------------------------------------------------------
// merged prep: 9x weight transpose (single bf16) | build_xm | bias concat
// ---------------------------------------------------------------------------
struct WJobs {
    const float* W[9];
    unsigned short* Wh[9];
    int K[9];
    int N[9];
    int base[10];
};

__global__ __launch_bounds__(256) void prep_all_k(
    WJobs jb,
    const float* __restrict__ x, const float* __restrict__ meta,
    unsigned short* __restrict__ xh, unsigned short* __restrict__ xl,
    const float* __restrict__ bq, const float* __restrict__ bk,
    const float* __restrict__ bv, float* __restrict__ bqkv)
{
    __shared__ float tile[64][65];
    const int bid = blockIdx.x;
    const int tid = threadIdx.x;

    if (bid < 1088) {
        int j = 0;
        while (bid >= jb.base[j + 1]) ++j;
        const int local = bid - jb.base[j];
        const int K = jb.K[j], N = jb.N[j];
        const int nx = N >> 6;
        const int k0 = (local / nx) * 64, n0 = (local % nx) * 64;
        const float* W = jb.W[j];
        unsigned short* Wh = jb.Wh[j];
        #pragma unroll
        for (int i = 0; i < 16; ++i) {
            int lin = i * 256 + tid;
            int kr = lin >> 6, nc = lin & 63;
            tile[kr][nc] = W[(size_t)(k0 + kr) * N + n0 + nc];
        }
        __syncthreads();
        #pragma unroll
        for (int i = 0; i < 16; ++i) {
            int lin = i * 256 + tid;
            int nr = lin >> 6, kc = lin & 63;
            Wh[(size_t)(n0 + nr) * K + k0 + kc] = f2bf(tile[kc][nr]);
        }
    } else if (bid < 3200) {
        int idx = (bid - 1088) * 256 + tid;   // float4 index over BT*128
        int row = idx >> 7, c4 = idx & 127;
        int b = row >= TT;
        int t = row - b * TT;
        float4 v = (t < MMETA) ? ((const float4*)(meta + (size_t)t * DD))[c4]
                               : ((const float4*)(x + ((size_t)b * SS + (t - MMETA)) * DD))[c4];
        ushort4 h, lo;
        h.x = f2bf(v.x); lo.x = f2bf(v.x - bf2f(h.x));
        h.y = f2bf(v.y); lo.y = f2bf(v.y - bf2f(h.y));
        h.z = f2bf(v.z); lo.z = f2bf(v.z - bf2f(h.z));
        h.w = f2bf(v.w); lo.w = f2bf(v.w - bf2f(h.w));
        ((ushort4*)xh)[idx] = h;
        ((ushort4*)xl)[idx] = lo;
    } else {
        int i = (bid - 3200) * 256 + tid;
        if (i < QKV_N) {
            float v;
            if (i < 512) v = bq[i];
            else if (i < 1024) v = bk[i - 512];
            else v = bv[i - 1024];
            bqkv[i] = v;
        }
    }
}

// ---------------------------------------------------------------------------
// MFMA GEMM: activations APLANES bf16 planes (2 = hi/lo, 1 = single),
//   weights single bf16. counted-vmcnt double-buffer; grid 66*GN.
//   EPI: 0 bias->fp32; 1 silu->hi/lo; 4 qkv dual + vt transpose;
//        5 silu->single bf16; 6 res(single)+silu->single bf16
// ---------------------------------------------------------------------------
template<int APLANES, int BN, int GN, int EPI, bool DROPMETA>
__global__ __launch_bounds__(256, 3) void gemm_mfma_k(
    const unsigned short* __restrict__ Ah, const unsigned short* __restrict__ Al,
    const unsigned short* __restrict__ Wh,
    const float* __restrict__ bias,
    const unsigned short* __restrict__ resh,
    float* __restrict__ outf, unsigned short* __restrict__ outh,
    unsigned short* __restrict__ outl,
    unsigned short* __restrict__ vth, unsigned short* __restrict__ vtl,
    int K, int N)
{
    constexpr int BM = 64;
    constexpr int MF = 2;              // wave covers 32 rows
    constexpr int NF = BN / 32;        // wave covers BN/2 cols
    constexpr int ABYTES = BM * 64;    // 4 KB per A plane
    constexpr int BBYTES = BN * 64;    // single B plane
    constexpr int BUFB = APLANES * ABYTES + BBYTES;
    constexpr int LOADS = APLANES + BN / 64;   // per-thread loads per stage
    __shared__ short8v smem_v[(2 * BUFB) / 16];
    char* smem = (char*)smem_v;

    // XCD-chunk swizzle (bijective since NWG % 8 == 0)
    constexpr int NWG = 66 * GN;
    const int orig = blockIdx.x;
    const int swz = (orig & 7) * (NWG >> 3) + (orig >> 3);
    const int row0 = (swz / GN) * BM;
    const int n0 = (swz % GN) * BN;

    const int tid = threadIdx.x;
    const int l = tid & 63, wid = tid >> 6;
    const int wm = wid >> 1, wn = wid & 1;
    const int lr = l & 15, lg = l >> 4;

    const char* Ahg0 = (const char*)Ah + (size_t)row0 * K * 2;
    const char* Alg0 = (APLANES == 2) ? (const char*)Al + (size_t)row0 * K * 2 : nullptr;
    const char* Whg  = (const char*)Wh + (size_t)n0 * K * 2;

    // conflict-free swizzle: sigma(r) = (r>>1)&3 over the 4 16B segs of a row
    int a_off[MF], b_off[NF];
    #pragma unroll
    for (int mf = 0; mf < MF; ++mf) {
        int r = wm * 32 + mf * 16 + lr;
        a_off[mf] = r * 64 + ((lg * 16) ^ (((r >> 1) & 3) << 4));
    }
    #pragma unroll
    for (int nf = 0; nf < NF; ++nf) {
        int r = wn * (BN / 2) + nf * 16 + lr;
        b_off[nf] = r * 64 + ((lg * 16) ^ (((r >> 1) & 3) << 4));
    }

    f32x4 acc[MF][NF];
    #pragma unroll
    for (int mf = 0; mf < MF; ++mf)
        #pragma unroll
        for (int nf = 0; nf < NF; ++nf) acc[mf][nf] = (f32x4){0.f, 0.f, 0.f, 0.f};

    const int NT = K / 32;

    auto stage = [&](int buf, int t) {
        char* lb = smem + buf * BUFB;
        const size_t kb = (size_t)t * 64;
        {
            int off = tid * 16;
            int row = off >> 6;
            int sc = (off & 63) ^ (((row >> 1) & 3) << 4);
            size_t gb = (size_t)row * (K * 2) + kb + sc;
            gload_lds16(Ahg0 + gb, lb + off);
            if (APLANES == 2)
                gload_lds16(Alg0 + gb, lb + ABYTES + off);
        }
        #pragma unroll
        for (int it = 0; it < BBYTES / 4096; ++it) {
            int off = (it * 256 + tid) * 16;
            int row = off >> 6;
            int sc = (off & 63) ^ (((row >> 1) & 3) << 4);
            size_t gb = (size_t)row * (K * 2) + kb + sc;
            gload_lds16(Whg + gb, lb + APLANES * ABYTES + off);
        }
    };

    stage(0, 0);

    int cur = 0;
    for (int t = 0; t < NT; ++t) {
        if (t + 1 < NT) {
            stage(cur ^ 1, t + 1);
            vm_wait<LOADS>();        // wait only tile t's loads; t+1 stays in flight
        } else {
            vm_wait<0>();
        }
        __builtin_amdgcn_s_barrier();
        __builtin_amdgcn_sched_barrier(0);

        char* lb = smem + cur * BUFB;
        short8v ah[MF], al[MF], bh[NF];
        #pragma unroll
        for (int mf = 0; mf < MF; ++mf) {
            ah[mf] = *(const short8v*)(lb + a_off[mf]);
            if (APLANES == 2)
                al[mf] = *(const short8v*)(lb + ABYTES + a_off[mf]);
        }
        #pragma unroll
        for (int nf = 0; nf < NF; ++nf)
            bh[nf] = *(const short8v*)(lb + APLANES * ABYTES + b_off[nf]);
        __builtin_amdgcn_s_setprio(1);
        #pragma unroll
        for (int mf = 0; mf < MF; ++mf)
            #pragma unroll
            for (int nf = 0; nf < NF; ++nf) {
                acc[mf][nf] = __builtin_amdgcn_mfma_f32_16x16x32_bf16(ah[mf], bh[nf], acc[mf][nf], 0, 0, 0);
                if (APLANES == 2)
                    acc[mf][nf] = __builtin_amdgcn_mfma_f32_16x16x32_bf16(al[mf], bh[nf], acc[mf][nf], 0, 0, 0);
            }
        __builtin_amdgcn_s_setprio(0);
        __builtin_amdgcn_s_barrier();    // all reads of buf[cur] done before overwrite
        cur ^= 1;
    }

    // epilogue: C/D layout col = lane&15, row = (lane>>4)*4 + reg
    #pragma unroll
    for (int mf = 0; mf < MF; ++mf) {
        #pragma unroll
        for (int nf = 0; nf < NF; ++nf) {
            int col = n0 + wn * (BN / 2) + nf * 16 + lr;
            float bv = bias[col];
            if (EPI == 4 && col >= 1024) {
                unsigned short hv[4], lv[4];
                #pragma unroll
                for (int j = 0; j < 4; ++j) {
                    float v = acc[mf][nf][j] + bv;
                    unsigned short hi = f2bf(v);
                    hv[j] = hi; lv[j] = f2bf(v - bf2f(hi));
                }
                int dg = col - 1024;
                size_t tok = (size_t)row0 + wm * 32 + mf * 16 + lg * 4;
                *(ushort4*)(vth + (size_t)dg * BT + tok) = *(ushort4*)hv;
                *(ushort4*)(vtl + (size_t)dg * BT + tok) = *(ushort4*)lv;
            } else {
                #pragma unroll
                for (int j = 0; j < 4; ++j) {
                    int row = row0 + wm * 32 + mf * 16 + lg * 4 + j;
                    float v = acc[mf][nf][j] + bv;
                    if (EPI == 1 || EPI == 5 || EPI == 6) v = v / (1.f + __expf(-v));
                    size_t idx = (size_t)row * N + col;
                    if (EPI == 6) v += bf2f(resh[idx]);
                    if (EPI == 0) {
                        if (DROPMETA) {
                            int b = row >= TT;
                            int t2 = row - b * TT;
                            if (t2 >= MMETA)
                                outf[((size_t)b * SS + (t2 - MMETA)) * N + col] = v;
                        } else {
                            outf[idx] = v;
                        }
                    } else if (EPI == 5 || EPI == 6) {
                        outh[idx] = f2bf(v);
                    } else {
                        unsigned short hi = f2bf(v);
                        outh[idx] = hi;
                        outl[idx] = f2bf(v - bf2f(hi));
                    }
                }
            }
        }
    }
}

// ---------------------------------------------------------------------------
// causal depthwise conv (K=4) + L2 normalize; 8 rows/block with LDS row reuse.
// ---------------------------------------------------------------------------
__global__ __launch_bounds__(256) void conv_norm8_k(
    const float* __restrict__ qlin, const float* __restrict__ convw,
    unsigned short* __restrict__ qh, unsigned short* __restrict__ ql)
{
    __shared__ float qs[11][512];
    const int tid = threadIdx.x;
    const int r0 = blockIdx.x * 8;               // 2112 % 8 == 0: no batch straddle
    const int b = r0 >= TT;
    const int bstart = b * TT;

    const float4* ql4 = (const float4*)qlin;
    for (int i = tid; i < 11 * 128; i += 256) {
        int lrow = i >> 7, c4 = i & 127;
        int grow = r0 - 3 + lrow;
        float4 v = (grow >= bstart) ? ql4[(size_t)grow * 128 + c4]
                                    : (float4){0.f, 0.f, 0.f, 0.f};
        ((float4*)qs[lrow])[c4] = v;
    }
    __syncthreads();

    const int w = tid >> 6, lane = tid & 63;
    const int d0 = lane * 8;

    #pragma unroll
    for (int e = 0; e < 2; ++e) {
        const int lrow = w * 2 + e;              // 0..7
        const int rowg = r0 + lrow;
        float vals[8];
        #pragma unroll
        for (int j = 0; j < 8; ++j) vals[j] = 0.f;
        #pragma unroll
        for (int k = 0; k < KCONV; ++k) {
            const float* src = qs[lrow + k];
            const float* cw = convw + k * DD + d0;
            #pragma unroll
            for (int j = 0; j < 8; ++j)
                vals[j] += src[d0 + j] * cw[j];
        }
        float ss = 0.f;
        #pragma unroll
        for (int j = 0; j < 8; ++j) ss += vals[j] * vals[j];
        #pragma unroll
        for (int off = 32; off > 0; off >>= 1)
            ss += __shfl_xor(ss, off);
        float inv = 1.f / fmaxf(sqrtf(ss), 1e-12f);
        unsigned short hv[8], lv[8];
        #pragma unroll
        for (int j = 0; j < 8; ++j) {
            float v = vals[j] * inv;
            unsigned short hi = f2bf(v);
            hv[j] = hi;
            lv[j] = f2bf(v - bf2f(hi));
        }
        size_t base = (size_t)rowg * DD + d0;
        *(ushort4*)(qh + base) = *(ushort4*)hv;
        *(ushort4*)(qh + base + 4) = *(ushort4*)(hv + 4);
        *(ushort4*)(ql + base) = *(ushort4*)lv;
        *(ushort4*)(ql + base + 4) = *(ushort4*)(lv + 4);
    }
}

// ---------------------------------------------------------------------------
// Flash sliding-window attention, MFMA, V^T staged from global. (unchanged)
// ---------------------------------------------------------------------------
__global__ __launch_bounds__(256, 2) void swa_flash_k(
    const unsigned short* __restrict__ qkvh, const unsigned short* __restrict__ qkvl,
    const unsigned short* __restrict__ vth, const unsigned short* __restrict__ vtl,
    unsigned short* __restrict__ oh, unsigned short* __restrict__ ol)
{
    // LDS: Kh 8192 | Kl 8192 | Vh 8192 | Vl 8192 | P 4x2304
    __shared__ short8v lds_v[41984 / 16];
    char* lds = (char*)lds_v;
    char* Kh_lds = lds;
    char* Kl_lds = lds + 8192;
    char* Vh_lds = lds + 16384;
    char* Vl_lds = lds + 24576;
    char* P_lds  = lds + 32768;

    const int tid = threadIdx.x;
    const int lane = tid & 63, w = tid >> 6;
    const int l15 = lane & 15, lg = lane >> 4;
    const int q0 = blockIdx.x * 64;
    const int h = blockIdx.y, b = blockIdx.z;
    const int rowbase = b * TT;

    const int qrow = rowbase + q0 + w * 16 + l15;
    short8v qhf[2], qlf[2];
    #pragma unroll
    for (int kh = 0; kh < 2; ++kh) {
        size_t off = (size_t)qrow * QKV_N + h * 64 + kh * 32 + lg * 8;
        qhf[kh] = *(const short8v*)(qkvh + off);
        qlf[kh] = *(const short8v*)(qkvl + off);
    }

    f32x4 o_acc[4];
    #pragma unroll
    for (int td = 0; td < 4; ++td) o_acc[td] = (f32x4){0.f, 0.f, 0.f, 0.f};
    float m_r[4], l_r[4];
    #pragma unroll
    for (int r = 0; r < 4; ++r) { m_r[r] = -1e30f; l_r[r] = 0.f; }

    char* Pw = P_lds + w * 2304;   // per-wave [16][72] bf16

    for (int kt = 0; kt < 5; ++kt) {
        const int kst = q0 - 256 + kt * 64;
        if (kst + 64 <= 0) continue;
        __syncthreads();
        #pragma unroll
        for (int it = 0; it < 2; ++it) {
            int lin = it * 256 + tid;
            int r = lin >> 3, seg = lin & 7;
            int colb = (seg * 16) ^ ((r & 7) << 4);
            size_t gb = ((size_t)(rowbase + kst + r) * QKV_N + 512 + h * 64) * 2 + colb;
            gload_lds16((const char*)qkvh + gb, Kh_lds + lin * 16);
            gload_lds16((const char*)qkvl + gb, Kl_lds + lin * 16);
        }
        #pragma unroll
        for (int it = 0; it < 2; ++it) {
            int lin = it * 256 + tid;
            int dd = lin >> 3, seg = lin & 7;
            int colb = (seg * 16) ^ ((dd & 7) << 4);
            size_t gb = ((size_t)(h * 64 + dd) * BT + rowbase + kst) * 2 + colb;
            gload_lds16((const char*)vth + gb, Vh_lds + lin * 16);
            gload_lds16((const char*)vtl + gb, Vl_lds + lin * 16);
        }
        __syncthreads();

        f32x4 s_fr[4];
        #pragma unroll
        for (int tj = 0; tj < 4; ++tj) s_fr[tj] = (f32x4){0.f, 0.f, 0.f, 0.f};
        #pragma unroll
        for (int tj = 0; tj < 4; ++tj) {
            int j = tj * 16 + l15;
            #pragma unroll
            for (int kh = 0; kh < 2; ++kh) {
                int colb = (kh * 64 + lg * 16) ^ ((j & 7) << 4);
                short8v kbh = *(const short8v*)(Kh_lds + j * 128 + colb);
                short8v kbl = *(const short8v*)(Kl_lds + j * 128 + colb);
                s_fr[tj] = __builtin_amdgcn_mfma_f32_16x16x32_bf16(qhf[kh], kbh, s_fr[tj], 0, 0, 0);
                s_fr[tj] = __builtin_amdgcn_mfma_f32_16x16x32_bf16(qhf[kh], kbl, s_fr[tj], 0, 0, 0);
                s_fr[tj] = __builtin_amdgcn_mfma_f32_16x16x32_bf16(qlf[kh], kbh, s_fr[tj], 0, 0, 0);
            }
        }
        #pragma unroll
        for (int tj = 0; tj < 4; ++tj) {
            int j = kst + tj * 16 + l15;
            #pragma unroll
            for (int r = 0; r < 4; ++r) {
                int i = q0 + w * 16 + lg * 4 + r;
                bool valid = (j <= i) && (i - j < WINN);
                s_fr[tj][r] = valid ? s_fr[tj][r] * 0.125f : -1e30f;
            }
        }
        float mx[4];
        #pragma unroll
        for (int r = 0; r < 4; ++r) {
            mx[r] = fmaxf(fmaxf(s_fr[0][r], s_fr[1][r]), fmaxf(s_fr[2][r], s_fr[3][r]));
            #pragma unroll
            for (int msk = 1; msk <= 8; msk <<= 1)
                mx[r] = fmaxf(mx[r], __shfl_xor(mx[r], msk));
            float mn = fmaxf(m_r[r], mx[r]);
            float sc = __expf(m_r[r] - mn);
            m_r[r] = mn;
            l_r[r] *= sc;
            #pragma unroll
            for (int td = 0; td < 4; ++td) o_acc[td][r] *= sc;
        }
        float rs[4] = {0.f, 0.f, 0.f, 0.f};
        #pragma unroll
        for (int tj = 0; tj < 4; ++tj) {
            #pragma unroll
            for (int r = 0; r < 4; ++r) {
                float p = __expf(s_fr[tj][r] - m_r[r]);
                rs[r] += p;
                ((unsigned short*)Pw)[(lg * 4 + r) * 72 + tj * 16 + l15] = f2bf(p);
            }
        }
        #pragma unroll
        for (int r = 0; r < 4; ++r) {
            #pragma unroll
            for (int msk = 1; msk <= 8; msk <<= 1)
                rs[r] += __shfl_xor(rs[r], msk);
            l_r[r] += rs[r];
        }
        short8v pa[2];
        #pragma unroll
        for (int jh = 0; jh < 2; ++jh)
            pa[jh] = *(const short8v*)(Pw + l15 * 144 + jh * 64 + lg * 16);
        #pragma unroll
        for (int td = 0; td < 4; ++td) {
            int drow = td * 16 + l15;
            #pragma unroll
            for (int jh = 0; jh < 2; ++jh) {
                int colb = (jh * 64 + lg * 16) ^ ((drow & 7) << 4);
                short8v vfh = *(const short8v*)(Vh_lds + drow * 128 + colb);
                short8v vfl = *(const short8v*)(Vl_lds + drow * 128 + colb);
                o_acc[td] = __builtin_amdgcn_mfma_f32_16x16x32_bf16(pa[jh], vfh, o_acc[td], 0, 0, 0);
                o_acc[td] = __builtin_amdgcn_mfma_f32_16x16x32_bf16(pa[jh], vfl, o_acc[td], 0, 0, 0);
            }
        }
    }

    #pragma unroll
    for (int r = 0; r < 4; ++r) {
        float inv = 1.f / l_r[r];
        int row = rowbase + q0 + w * 16 + lg * 4 + r;
        #pragma unroll
        for (int td = 0; td < 4; ++td) {
            float v = o_acc[td][r] * inv;
            size_t idx = (size_t)row * DD + h * 64 + td * 16 + l15;
            unsigned short hi = f2bf(v);
            oh[idx] = hi;
            ol[idx] = f2bf(v - bf2f(hi));
        }
    }
}

// ---------------------------------------------------------------------------
// Launch
// ---------------------------------------------------------------------------
extern "C" void kernel_launch(void* const* d_in, const int* in_sizes, int n_in,
                              void* d_out, int out_size, void* d_ws, size_t ws_size,
                              hipStream_t stream)
{
    const float* x       = (const float*)d_in[0];
    const float* meta    = (const float*)d_in[1];
    const float* qp_w    = (const float*)d_in[2];
    const float* qp_b    = (const float*)d_in[3];
    const float* qp_conv = (const float*)d_in[4];
    const float* w_in    = (const float*)d_in[5];
    const float* b_in    = (const float*)d_in[6];
    const float* w_hid   = (const float*)d_in[7];
    const float* b_hid   = (const float*)d_in[8];
    const float* w_out   = (const float*)d_in[9];
    const float* b_out   = (const float*)d_in[10];
    const float* wq      = (const float*)d_in[11];
    const float* bq      = (const float*)d_in[12];
    const float* wk      = (const float*)d_in[13];
    const float* bk      = (const float*)d_in[14];
    const float* wv      = (const float*)d_in[15];
    const float* bv      = (const float*)d_in[16];
    const float* wo      = (const float*)d_in[17];
    const float* bo      = (const float*)d_in[18];
    float* out = (float*)d_out;

    typedef unsigned short us;
    char* p = (char*)d_ws;
    auto alloc = [&](size_t n) { char* r = p; p += (n + 255) & ~(size_t)255; return r; };

    // weights: single bf16, transposed [N][K]
    us* wqp_h   = (us*)alloc(512 * 512 * 2);
    us* win_h   = (us*)alloc(512 * 1024 * 2);
    us* whid0_h = (us*)alloc(1024 * 1024 * 2);
    us* whid1_h = (us*)alloc(1024 * 1024 * 2);
    us* wout_h  = (us*)alloc(1024 * 512 * 2);
    us* wqkv_h  = (us*)alloc((size_t)QKV_N * 512 * 2);
    us* wo_h    = (us*)alloc(512 * 512 * 2);
    float* bqkv = (float*)alloc(QKV_N * 4);

    const size_t H512 = (size_t)BT * 512 * 2;    // 4.3 MB (bf16 plane, 512 cols)
    const size_t H1024 = (size_t)BT * 1024 * 2;  // 8.65 MB
    char* RA = alloc(2 * H512);    // xm hi/lo  -> later ob hi/lo
    char* RB = alloc((size_t)BT * 512 * 4);   // qlin fp32
    char* RC = alloc(2 * H512);    // qn hi/lo -> r hi/lo
    char* RD1 = alloc(H1024);      // ha single -> hc single
    char* RD2 = alloc(H1024);      // hb single
    char* RF = alloc(2 * (size_t)BT * QKV_N * 2);   // qkv hi/lo (q,k cols used)
    char* RE = alloc(2 * H512);    // vt hi/lo ([512][BT] each)

    us* xm_h = (us*)RA;   us* xm_l = (us*)(RA + H512);
    float* qlin = (float*)RB;
    us* qn_h = (us*)RC;   us* qn_l = (us*)(RC + H512);
    us* ha = (us*)RD1;
    us* hb = (us*)RD2;
    us* hc = (us*)RD1;    // overlay ha (dead after whid0)
    us* r_h  = qn_h;      us* r_l  = qn_l;
    us* qkv_h = (us*)RF;  us* qkv_l = (us*)(RF + (size_t)BT * QKV_N * 2);
    us* vt_h  = (us*)RE;  us* vt_l  = (us*)(RE + H512);
    us* ob_h = (us*)RA;   us* ob_l = (us*)(RA + H512);

    // --- merged prep: wsplit (1088) + build_xm (2112) + bias (6) ---
    WJobs jb;
    const float* Ws[9]   = {qp_w, w_in, w_hid, w_hid + (size_t)1024 * 1024, w_out,
                            wq, wk, wv, wo};
    us* Whs[9] = {wqp_h, win_h, whid0_h, whid1_h, wout_h,
                  wqkv_h, wqkv_h + 512 * 512, wqkv_h + 2 * 512 * 512, wo_h};
    int Ks[9] = {512, 512, 1024, 1024, 1024, 512, 512, 512, 512};
    int Ns[9] = {512, 1024, 1024, 1024, 512, 512, 512, 512, 512};
    int acc_t = 0;
    for (int j = 0; j < 9; ++j) {
        jb.W[j] = Ws[j]; jb.Wh[j] = Whs[j];
        jb.K[j] = Ks[j]; jb.N[j] = Ns[j];
        jb.base[j] = acc_t;
        acc_t += (Ks[j] / 64) * (Ns[j] / 64);
    }
    jb.base[9] = acc_t;    // 1088
    prep_all_k<<<3206, 256, 0, stream>>>(jb, x, meta, xm_h, xm_l, bq, bk, bv, bqkv);

    // --- pipeline ---
    // qlin = xm @ qp_w + b (fp32 out): A dual, N=512, BN=64, grid 528
    gemm_mfma_k<2, 64, 8, 0, false><<<528, 256, 0, stream>>>(
        xm_h, xm_l, wqp_h, qp_b, nullptr, qlin, nullptr, nullptr, nullptr, nullptr, 512, 512);
    conv_norm8_k<<<BT / 8, 256, 0, stream>>>(qlin, qp_conv, qn_h, qn_l);
    // ha = silu(qn @ w_in + b_in): A dual -> single out, BN=128, grid 528
    gemm_mfma_k<2, 128, 8, 5, false><<<528, 256, 0, stream>>>(
        qn_h, qn_l, win_h, b_in, nullptr, nullptr, ha, nullptr, nullptr, nullptr, 512, 1024);
    // hb = ha + silu(ha @ whid0 + b0): A single -> single out
    gemm_mfma_k<1, 128, 8, 6, false><<<528, 256, 0, stream>>>(
        ha, nullptr, whid0_h, b_hid, ha, nullptr, hb, nullptr, nullptr, nullptr, 1024, 1024);
    // hc = hb + silu(hb @ whid1 + b1): A single -> single out
    gemm_mfma_k<1, 128, 8, 6, false><<<528, 256, 0, stream>>>(
        hb, nullptr, whid1_h, b_hid + HH, hb, nullptr, hc, nullptr, nullptr, nullptr, 1024, 1024);
    // r = silu(hc @ w_out + b_out): A single -> hi/lo out, BN=64, grid 528
    gemm_mfma_k<1, 64, 8, 1, false><<<528, 256, 0, stream>>>(
        hc, nullptr, wout_h, b_out, nullptr, nullptr, r_h, r_l, nullptr, nullptr, 1024, 512);
    // fused q/k/v projection: A dual, N=1536, BN=128, grid 792
    gemm_mfma_k<2, 128, 12, 4, false><<<792, 256, 0, stream>>>(
        r_h, r_l, wqkv_h, bqkv, nullptr, nullptr, qkv_h, qkv_l, vt_h, vt_l, 512, QKV_N);
    // flash sliding-window attention
    swa_flash_k<<<dim3(TT / 64, NHH, BB), 256, 0, stream>>>(qkv_h, qkv_l, vt_h, vt_l, ob_h, ob_l);
    // out = (ob @ wo + bo)[t >= M]: A dual, N=512, BN=64, grid 528
    gemm_mfma_k<2, 64, 8, 0, true><<<528, 256, 0, stream>>>(
        ob_h, ob_l, wo_h, bo, nullptr, out, nullptr, nullptr, nullptr, nullptr, 512, 512);
}

// Round 15
// 144.395 us; speedup vs baseline: 3.3239x; 1.1401x over previous
//
#include <hip/hip_runtime.h>
#include <math.h>
#include <stdint.h>

#define BB 2
#define SS 2048
#define DD 512
#define HH 1024
#define MMETA 64
#define KCONV 4
#define NHH 8
#define DHH 64
#define WINN 256
#define TT (MMETA + SS)     // 2112
#define BT (BB * TT)        // 4224
#define QKV_N 1536

typedef __attribute__((ext_vector_type(8))) short short8v;   // 8 bf16 = 4 VGPR
typedef __attribute__((ext_vector_type(4))) float f32x4;

__device__ __forceinline__ unsigned short f2bf(float f) {
    union { float f; unsigned u; } c; c.f = f;
    unsigned u = c.u;
    unsigned r = (u + 0x7fffu + ((u >> 16) & 1u)) >> 16;   // RNE
    return (unsigned short)r;
}
__device__ __forceinline__ float bf2f(unsigned short h) {
    union { unsigned u; float f; } c; c.u = ((unsigned)h) << 16;
    return c.f;
}

__device__ __forceinline__ void gload_lds16(const void* g, void* l) {
    __builtin_amdgcn_global_load_lds(
        (const __attribute__((address_space(1))) unsigned int*)g,
        (__attribute__((address_space(3))) unsigned int*)l, 16, 0, 0);
}

// counted vmcnt wait (T4)
template<int N>
__device__ __forceinline__ void vm_wait() {
    if constexpr (N == 0)      asm volatile("s_waitcnt vmcnt(0)" ::: "memory");
    else if constexpr (N == 2) asm volatile("s_waitcnt vmcnt(2)" ::: "memory");
    else if constexpr (N == 3) asm volatile("s_waitcnt vmcnt(3)" ::: "memory");
    else static_assert(N == 0, "unsupported vmcnt");
}

// ---------------------------------------------------------------------------
// merged prep: 9x weight transpose (single bf16) | build_xm (single) | bias
// ---------------------------------------------------------------------------
struct WJobs {
    const float* W[9];
    unsigned short* Wh[9];
    int K[9];
    int N[9];
    int base[10];
};

__global__ __launch_bounds__(256) void prep_all_k(
    WJobs jb,
    const float* __restrict__ x, const float* __restrict__ meta,
    unsigned short* __restrict__ xh,
    const float* __restrict__ bq, const float* __restrict__ bk,
    const float* __restrict__ bv, float* __restrict__ bqkv)
{
    __shared__ float tile[64][65];
    const int bid = blockIdx.x;
    const int tid = threadIdx.x;

    if (bid < 1088) {
        int j = 0;
        while (bid >= jb.base[j + 1]) ++j;
        const int local = bid - jb.base[j];
        const int K = jb.K[j], N = jb.N[j];
        const int nx = N >> 6;
        const int k0 = (local / nx) * 64, n0 = (local % nx) * 64;
        const float* W = jb.W[j];
        unsigned short* Wh = jb.Wh[j];
        #pragma unroll
        for (int i = 0; i < 16; ++i) {
            int lin = i * 256 + tid;
            int kr = lin >> 6, nc = lin & 63;
            tile[kr][nc] = W[(size_t)(k0 + kr) * N + n0 + nc];
        }
        __syncthreads();
        #pragma unroll
        for (int i = 0; i < 16; ++i) {
            int lin = i * 256 + tid;
            int nr = lin >> 6, kc = lin & 63;
            Wh[(size_t)(n0 + nr) * K + k0 + kc] = f2bf(tile[kc][nr]);
        }
    } else if (bid < 3200) {
        int idx = (bid - 1088) * 256 + tid;   // float4 index over BT*128
        int row = idx >> 7, c4 = idx & 127;
        int b = row >= TT;
        int t = row - b * TT;
        float4 v = (t < MMETA) ? ((const float4*)(meta + (size_t)t * DD))[c4]
                               : ((const float4*)(x + ((size_t)b * SS + (t - MMETA)) * DD))[c4];
        ushort4 h;
        h.x = f2bf(v.x); h.y = f2bf(v.y); h.z = f2bf(v.z); h.w = f2bf(v.w);
        ((ushort4*)xh)[idx] = h;
    } else {
        int i = (bid - 3200) * 256 + tid;
        if (i < QKV_N) {
            float v;
            if (i < 512) v = bq[i];
            else if (i < 1024) v = bk[i - 512];
            else v = bv[i - 1024];
            bqkv[i] = v;
        }
    }
}

// ---------------------------------------------------------------------------
// MFMA GEMM: single-bf16 activations & weights (1 MFMA per fragment pair).
//   counted-vmcnt double-buffer (T4); grid 66*GN, XCD swizzle.
//   EPI: 0 bias->fp32; 4 qkv: cols<1024 -> hi/lo split, cols>=1024 -> vt single;
//        5 silu->single bf16; 6 res(single)+silu->single bf16
// ---------------------------------------------------------------------------
template<int BN, int GN, int EPI, bool DROPMETA>
__global__ __launch_bounds__(256, 3) void gemm_mfma_k(
    const unsigned short* __restrict__ Ah,
    const unsigned short* __restrict__ Wh,
    const float* __restrict__ bias,
    const unsigned short* __restrict__ resh,
    float* __restrict__ outf, unsigned short* __restrict__ outh,
    unsigned short* __restrict__ outl,
    unsigned short* __restrict__ vth,
    int K, int N)
{
    constexpr int BM = 64;
    constexpr int MF = 2;              // wave covers 32 rows
    constexpr int NF = BN / 32;        // wave covers BN/2 cols
    constexpr int ABYTES = BM * 64;    // 4 KB
    constexpr int BBYTES = BN * 64;
    constexpr int BUFB = ABYTES + BBYTES;
    constexpr int LOADS = 1 + BN / 64; // per-thread loads per stage
    __shared__ short8v smem_v[(2 * BUFB) / 16];
    char* smem = (char*)smem_v;

    // XCD-chunk swizzle (bijective since NWG % 8 == 0)
    constexpr int NWG = 66 * GN;
    const int orig = blockIdx.x;
    const int swz = (orig & 7) * (NWG >> 3) + (orig >> 3);
    const int row0 = (swz / GN) * BM;
    const int n0 = (swz % GN) * BN;

    const int tid = threadIdx.x;
    const int l = tid & 63, wid = tid >> 6;
    const int wm = wid >> 1, wn = wid & 1;
    const int lr = l & 15, lg = l >> 4;

    const char* Ahg0 = (const char*)Ah + (size_t)row0 * K * 2;
    const char* Whg  = (const char*)Wh + (size_t)n0 * K * 2;

    // conflict-free swizzle: sigma(r) = (r>>1)&3 over the 4 16B segs of a row
    int a_off[MF], b_off[NF];
    #pragma unroll
    for (int mf = 0; mf < MF; ++mf) {
        int r = wm * 32 + mf * 16 + lr;
        a_off[mf] = r * 64 + ((lg * 16) ^ (((r >> 1) & 3) << 4));
    }
    #pragma unroll
    for (int nf = 0; nf < NF; ++nf) {
        int r = wn * (BN / 2) + nf * 16 + lr;
        b_off[nf] = r * 64 + ((lg * 16) ^ (((r >> 1) & 3) << 4));
    }

    f32x4 acc[MF][NF];
    #pragma unroll
    for (int mf = 0; mf < MF; ++mf)
        #pragma unroll
        for (int nf = 0; nf < NF; ++nf) acc[mf][nf] = (f32x4){0.f, 0.f, 0.f, 0.f};

    const int NT = K / 32;

    auto stage = [&](int buf, int t) {
        char* lb = smem + buf * BUFB;
        const size_t kb = (size_t)t * 64;
        {
            int off = tid * 16;
            int row = off >> 6;
            int sc = (off & 63) ^ (((row >> 1) & 3) << 4);
            size_t gb = (size_t)row * (K * 2) + kb + sc;
            gload_lds16(Ahg0 + gb, lb + off);
        }
        #pragma unroll
        for (int it = 0; it < BBYTES / 4096; ++it) {
            int off = (it * 256 + tid) * 16;
            int row = off >> 6;
            int sc = (off & 63) ^ (((row >> 1) & 3) << 4);
            size_t gb = (size_t)row * (K * 2) + kb + sc;
            gload_lds16(Whg + gb, lb + ABYTES + off);
        }
    };

    stage(0, 0);

    int cur = 0;
    for (int t = 0; t < NT; ++t) {
        if (t + 1 < NT) {
            stage(cur ^ 1, t + 1);
            vm_wait<LOADS>();        // wait only tile t's loads; t+1 stays in flight
        } else {
            vm_wait<0>();
        }
        __builtin_amdgcn_s_barrier();
        __builtin_amdgcn_sched_barrier(0);

        char* lb = smem + cur * BUFB;
        short8v ah[MF], bh[NF];
        #pragma unroll
        for (int mf = 0; mf < MF; ++mf)
            ah[mf] = *(const short8v*)(lb + a_off[mf]);
        #pragma unroll
        for (int nf = 0; nf < NF; ++nf)
            bh[nf] = *(const short8v*)(lb + ABYTES + b_off[nf]);
        __builtin_amdgcn_s_setprio(1);
        #pragma unroll
        for (int mf = 0; mf < MF; ++mf)
            #pragma unroll
            for (int nf = 0; nf < NF; ++nf)
                acc[mf][nf] = __builtin_amdgcn_mfma_f32_16x16x32_bf16(ah[mf], bh[nf], acc[mf][nf], 0, 0, 0);
        __builtin_amdgcn_s_setprio(0);
        __builtin_amdgcn_s_barrier();    // all reads of buf[cur] done before overwrite
        cur ^= 1;
    }

    // epilogue: C/D layout col = lane&15, row = (lane>>4)*4 + reg
    #pragma unroll
    for (int mf = 0; mf < MF; ++mf) {
        #pragma unroll
        for (int nf = 0; nf < NF; ++nf) {
            int col = n0 + wn * (BN / 2) + nf * 16 + lr;
            float bv = bias[col];
            if (EPI == 4 && col >= 1024) {
                // transposed v write: vt[d][token], single bf16
                unsigned short hv[4];
                #pragma unroll
                for (int j = 0; j < 4; ++j)
                    hv[j] = f2bf(acc[mf][nf][j] + bv);
                int dg = col - 1024;
                size_t tok = (size_t)row0 + wm * 32 + mf * 16 + lg * 4;
                *(ushort4*)(vth + (size_t)dg * BT + tok) = *(ushort4*)hv;
            } else {
                #pragma unroll
                for (int j = 0; j < 4; ++j) {
                    int row = row0 + wm * 32 + mf * 16 + lg * 4 + j;
                    float v = acc[mf][nf][j] + bv;
                    if (EPI == 5 || EPI == 6) v = v / (1.f + __expf(-v));
                    size_t idx = (size_t)row * N + col;
                    if (EPI == 6) v += bf2f(resh[idx]);
                    if (EPI == 0) {
                        if (DROPMETA) {
                            int b = row >= TT;
                            int t2 = row - b * TT;
                            if (t2 >= MMETA)
                                outf[((size_t)b * SS + (t2 - MMETA)) * N + col] = v;
                        } else {
                            outf[idx] = v;
                        }
                    } else if (EPI == 5 || EPI == 6) {
                        outh[idx] = f2bf(v);
                    } else {   // EPI == 4, q/k cols: hi/lo split
                        unsigned short hi = f2bf(v);
                        outh[idx] = hi;
                        outl[idx] = f2bf(v - bf2f(hi));
                    }
                }
            }
        }
    }
}

// ---------------------------------------------------------------------------
// causal depthwise conv (K=4) + L2 normalize; 8 rows/block; single bf16 out.
// ---------------------------------------------------------------------------
__global__ __launch_bounds__(256) void conv_norm8_k(
    const float* __restrict__ qlin, const float* __restrict__ convw,
    unsigned short* __restrict__ qh)
{
    __shared__ float qs[11][512];
    const int tid = threadIdx.x;
    const int r0 = blockIdx.x * 8;               // 2112 % 8 == 0: no batch straddle
    const int b = r0 >= TT;
    const int bstart = b * TT;

    const float4* ql4 = (const float4*)qlin;
    for (int i = tid; i < 11 * 128; i += 256) {
        int lrow = i >> 7, c4 = i & 127;
        int grow = r0 - 3 + lrow;
        float4 v = (grow >= bstart) ? ql4[(size_t)grow * 128 + c4]
                                    : (float4){0.f, 0.f, 0.f, 0.f};
        ((float4*)qs[lrow])[c4] = v;
    }
    __syncthreads();

    const int w = tid >> 6, lane = tid & 63;
    const int d0 = lane * 8;

    #pragma unroll
    for (int e = 0; e < 2; ++e) {
        const int lrow = w * 2 + e;              // 0..7
        const int rowg = r0 + lrow;
        float vals[8];
        #pragma unroll
        for (int j = 0; j < 8; ++j) vals[j] = 0.f;
        #pragma unroll
        for (int k = 0; k < KCONV; ++k) {
            const float* src = qs[lrow + k];
            const float* cw = convw + k * DD + d0;
            #pragma unroll
            for (int j = 0; j < 8; ++j)
                vals[j] += src[d0 + j] * cw[j];
        }
        float ss = 0.f;
        #pragma unroll
        for (int j = 0; j < 8; ++j) ss += vals[j] * vals[j];
        #pragma unroll
        for (int off = 32; off > 0; off >>= 1)
            ss += __shfl_xor(ss, off);
        float inv = 1.f / fmaxf(sqrtf(ss), 1e-12f);
        unsigned short hv[8];
        #pragma unroll
        for (int j = 0; j < 8; ++j)
            hv[j] = f2bf(vals[j] * inv);
        size_t base = (size_t)rowg * DD + d0;
        *(ushort4*)(qh + base) = *(ushort4*)hv;
        *(ushort4*)(qh + base + 4) = *(ushort4*)(hv + 4);
    }
}

// ---------------------------------------------------------------------------
// Flash sliding-window attention: Q/K hi/lo (bf16x3 QK^T), V single (1x PV).
// ---------------------------------------------------------------------------
__global__ __launch_bounds__(256, 2) void swa_flash_k(
    const unsigned short* __restrict__ qkvh, const unsigned short* __restrict__ qkvl,
    const unsigned short* __restrict__ vth,
    unsigned short* __restrict__ oh)
{
    // LDS: Kh 8192 | Kl 8192 | Vh 8192 | P 4x2304
    __shared__ short8v lds_v[33792 / 16];
    char* lds = (char*)lds_v;
    char* Kh_lds = lds;
    char* Kl_lds = lds + 8192;
    char* Vh_lds = lds + 16384;
    char* P_lds  = lds + 24576;

    const int tid = threadIdx.x;
    const int lane = tid & 63, w = tid >> 6;
    const int l15 = lane & 15, lg = lane >> 4;
    const int q0 = blockIdx.x * 64;
    const int h = blockIdx.y, b = blockIdx.z;
    const int rowbase = b * TT;

    const int qrow = rowbase + q0 + w * 16 + l15;
    short8v qhf[2], qlf[2];
    #pragma unroll
    for (int kh = 0; kh < 2; ++kh) {
        size_t off = (size_t)qrow * QKV_N + h * 64 + kh * 32 + lg * 8;
        qhf[kh] = *(const short8v*)(qkvh + off);
        qlf[kh] = *(const short8v*)(qkvl + off);
    }

    f32x4 o_acc[4];
    #pragma unroll
    for (int td = 0; td < 4; ++td) o_acc[td] = (f32x4){0.f, 0.f, 0.f, 0.f};
    float m_r[4], l_r[4];
    #pragma unroll
    for (int r = 0; r < 4; ++r) { m_r[r] = -1e30f; l_r[r] = 0.f; }

    char* Pw = P_lds + w * 2304;   // per-wave [16][72] bf16

    for (int kt = 0; kt < 5; ++kt) {
        const int kst = q0 - 256 + kt * 64;
        if (kst + 64 <= 0) continue;
        __syncthreads();
        #pragma unroll
        for (int it = 0; it < 2; ++it) {
            int lin = it * 256 + tid;
            int r = lin >> 3, seg = lin & 7;
            int colb = (seg * 16) ^ ((r & 7) << 4);
            size_t gb = ((size_t)(rowbase + kst + r) * QKV_N + 512 + h * 64) * 2 + colb;
            gload_lds16((const char*)qkvh + gb, Kh_lds + lin * 16);
            gload_lds16((const char*)qkvl + gb, Kl_lds + lin * 16);
        }
        #pragma unroll
        for (int it = 0; it < 2; ++it) {
            int lin = it * 256 + tid;
            int dd = lin >> 3, seg = lin & 7;
            int colb = (seg * 16) ^ ((dd & 7) << 4);
            size_t gb = ((size_t)(h * 64 + dd) * BT + rowbase + kst) * 2 + colb;
            gload_lds16((const char*)vth + gb, Vh_lds + lin * 16);
        }
        __syncthreads();

        f32x4 s_fr[4];
        #pragma unroll
        for (int tj = 0; tj < 4; ++tj) s_fr[tj] = (f32x4){0.f, 0.f, 0.f, 0.f};
        #pragma unroll
        for (int tj = 0; tj < 4; ++tj) {
            int j = tj * 16 + l15;
            #pragma unroll
            for (int kh = 0; kh < 2; ++kh) {
                int colb = (kh * 64 + lg * 16) ^ ((j & 7) << 4);
                short8v kbh = *(const short8v*)(Kh_lds + j * 128 + colb);
                short8v kbl = *(const short8v*)(Kl_lds + j * 128 + colb);
                s_fr[tj] = __builtin_amdgcn_mfma_f32_16x16x32_bf16(qhf[kh], kbh, s_fr[tj], 0, 0, 0);
                s_fr[tj] = __builtin_amdgcn_mfma_f32_16x16x32_bf16(qhf[kh], kbl, s_fr[tj], 0, 0, 0);
                s_fr[tj] = __builtin_amdgcn_mfma_f32_16x16x32_bf16(qlf[kh], kbh, s_fr[tj], 0, 0, 0);
            }
        }
        #pragma unroll
        for (int tj = 0; tj < 4; ++tj) {
            int j = kst + tj * 16 + l15;
            #pragma unroll
            for (int r = 0; r < 4; ++r) {
                int i = q0 + w * 16 + lg * 4 + r;
                bool valid = (j <= i) && (i - j < WINN);
                s_fr[tj][r] = valid ? s_fr[tj][r] * 0.125f : -1e30f;
            }
        }
        float mx[4];
        #pragma unroll
        for (int r = 0; r < 4; ++r) {
            mx[r] = fmaxf(fmaxf(s_fr[0][r], s_fr[1][r]), fmaxf(s_fr[2][r], s_fr[3][r]));
            #pragma unroll
            for (int msk = 1; msk <= 8; msk <<= 1)
                mx[r] = fmaxf(mx[r], __shfl_xor(mx[r], msk));
            float mn = fmaxf(m_r[r], mx[r]);
            float sc = __expf(m_r[r] - mn);
            m_r[r] = mn;
            l_r[r] *= sc;
            #pragma unroll
            for (int td = 0; td < 4; ++td) o_acc[td][r] *= sc;
        }
        float rs[4] = {0.f, 0.f, 0.f, 0.f};
        #pragma unroll
        for (int tj = 0; tj < 4; ++tj) {
            #pragma unroll
            for (int r = 0; r < 4; ++r) {
                float p = __expf(s_fr[tj][r] - m_r[r]);
                rs[r] += p;
                ((unsigned short*)Pw)[(lg * 4 + r) * 72 + tj * 16 + l15] = f2bf(p);
            }
        }
        #pragma unroll
        for (int r = 0; r < 4; ++r) {
            #pragma unroll
            for (int msk = 1; msk <= 8; msk <<= 1)
                rs[r] += __shfl_xor(rs[r], msk);
            l_r[r] += rs[r];
        }
        short8v pa[2];
        #pragma unroll
        for (int jh = 0; jh < 2; ++jh)
            pa[jh] = *(const short8v*)(Pw + l15 * 144 + jh * 64 + lg * 16);
        #pragma unroll
        for (int td = 0; td < 4; ++td) {
            int drow = td * 16 + l15;
            #pragma unroll
            for (int jh = 0; jh < 2; ++jh) {
                int colb = (jh * 64 + lg * 16) ^ ((drow & 7) << 4);
                short8v vfh = *(const short8v*)(Vh_lds + drow * 128 + colb);
                o_acc[td] = __builtin_amdgcn_mfma_f32_16x16x32_bf16(pa[jh], vfh, o_acc[td], 0, 0, 0);
            }
        }
    }

    #pragma unroll
    for (int r = 0; r < 4; ++r) {
        float inv = 1.f / l_r[r];
        int row = rowbase + q0 + w * 16 + lg * 4 + r;
        #pragma unroll
        for (int td = 0; td < 4; ++td) {
            float v = o_acc[td][r] * inv;
            oh[(size_t)row * DD + h * 64 + td * 16 + l15] = f2bf(v);
        }
    }
}

// ---------------------------------------------------------------------------
// Launch
// ---------------------------------------------------------------------------
extern "C" void kernel_launch(void* const* d_in, const int* in_sizes, int n_in,
                              void* d_out, int out_size, void* d_ws, size_t ws_size,
                              hipStream_t stream)
{
    const float* x       = (const float*)d_in[0];
    const float* meta    = (const float*)d_in[1];
    const float* qp_w    = (const float*)d_in[2];
    const float* qp_b    = (const float*)d_in[3];
    const float* qp_conv = (const float*)d_in[4];
    const float* w_in    = (const float*)d_in[5];
    const float* b_in    = (const float*)d_in[6];
    const float* w_hid   = (const float*)d_in[7];
    const float* b_hid   = (const float*)d_in[8];
    const float* w_out   = (const float*)d_in[9];
    const float* b_out   = (const float*)d_in[10];
    const float* wq      = (const float*)d_in[11];
    const float* bq      = (const float*)d_in[12];
    const float* wk      = (const float*)d_in[13];
    const float* bk      = (const float*)d_in[14];
    const float* wv      = (const float*)d_in[15];
    const float* bv      = (const float*)d_in[16];
    const float* wo      = (const float*)d_in[17];
    const float* bo      = (const float*)d_in[18];
    float* out = (float*)d_out;

    typedef unsigned short us;
    char* p = (char*)d_ws;
    auto alloc = [&](size_t n) { char* r = p; p += (n + 255) & ~(size_t)255; return r; };

    // weights: single bf16, transposed [N][K]
    us* wqp_h   = (us*)alloc(512 * 512 * 2);
    us* win_h   = (us*)alloc(512 * 1024 * 2);
    us* whid0_h = (us*)alloc(1024 * 1024 * 2);
    us* whid1_h = (us*)alloc(1024 * 1024 * 2);
    us* wout_h  = (us*)alloc(1024 * 512 * 2);
    us* wqkv_h  = (us*)alloc((size_t)QKV_N * 512 * 2);
    us* wo_h    = (us*)alloc(512 * 512 * 2);
    float* bqkv = (float*)alloc(QKV_N * 4);

    const size_t H512 = (size_t)BT * 512 * 2;    // 4.3 MB (bf16 plane, 512 cols)
    const size_t H1024 = (size_t)BT * 1024 * 2;  // 8.65 MB
    char* RA = alloc(H512);        // xm single -> later ob single
    char* RB = alloc((size_t)BT * 512 * 4);   // qlin fp32
    char* RC = alloc(H512);        // qn single -> r single
    char* RD1 = alloc(H1024);      // ha single -> hc single
    char* RD2 = alloc(H1024);      // hb single
    char* RF = alloc(2 * (size_t)BT * QKV_N * 2);   // qkv hi/lo (q,k cols used)
    char* RE = alloc(H512);        // vt single ([512][BT])

    us* xm = (us*)RA;
    float* qlin = (float*)RB;
    us* qn = (us*)RC;
    us* ha = (us*)RD1;
    us* hb = (us*)RD2;
    us* hc = (us*)RD1;    // overlay ha (dead after whid0)
    us* r  = qn;          // overlay qn (dead after win... actually qn dead after win GEMM)
    us* qkv_h = (us*)RF;  us* qkv_l = (us*)(RF + (size_t)BT * QKV_N * 2);
    us* vt = (us*)RE;
    us* ob = (us*)RA;     // overlay xm (dead after qlin GEMM)

    // --- merged prep: wsplit (1088) + build_xm (2112) + bias (6) ---
    WJobs jb;
    const float* Ws[9]   = {qp_w, w_in, w_hid, w_hid + (size_t)1024 * 1024, w_out,
                            wq, wk, wv, wo};
    us* Whs[9] = {wqp_h, win_h, whid0_h, whid1_h, wout_h,
                  wqkv_h, wqkv_h + 512 * 512, wqkv_h + 2 * 512 * 512, wo_h};
    int Ks[9] = {512, 512, 1024, 1024, 1024, 512, 512, 512, 512};
    int Ns[9] = {512, 1024, 1024, 1024, 512, 512, 512, 512, 512};
    int acc_t = 0;
    for (int j = 0; j < 9; ++j) {
        jb.W[j] = Ws[j]; jb.Wh[j] = Whs[j];
        jb.K[j] = Ks[j]; jb.N[j] = Ns[j];
        jb.base[j] = acc_t;
        acc_t += (Ks[j] / 64) * (Ns[j] / 64);
    }
    jb.base[9] = acc_t;    // 1088
    prep_all_k<<<3206, 256, 0, stream>>>(jb, x, meta, xm, bq, bk, bv, bqkv);

    // --- pipeline (all single-A GEMMs) ---
    // qlin = xm @ qp_w + b (fp32 out): N=512, BN=64, grid 528
    gemm_mfma_k<64, 8, 0, false><<<528, 256, 0, stream>>>(
        xm, wqp_h, qp_b, nullptr, qlin, nullptr, nullptr, nullptr, 512, 512);
    conv_norm8_k<<<BT / 8, 256, 0, stream>>>(qlin, qp_conv, qn);
    // ha = silu(qn @ w_in + b_in): BN=128, grid 528
    gemm_mfma_k<128, 8, 5, false><<<528, 256, 0, stream>>>(
        qn, win_h, b_in, nullptr, nullptr, ha, nullptr, nullptr, 512, 1024);
    // hb = ha + silu(ha @ whid0 + b0)
    gemm_mfma_k<128, 8, 6, false><<<528, 256, 0, stream>>>(
        ha, whid0_h, b_hid, ha, nullptr, hb, nullptr, nullptr, 1024, 1024);
    // hc = hb + silu(hb @ whid1 + b1)
    gemm_mfma_k<128, 8, 6, false><<<528, 256, 0, stream>>>(
        hb, whid1_h, b_hid + HH, hb, nullptr, hc, nullptr, nullptr, 1024, 1024);
    // r = silu(hc @ w_out + b_out): BN=64, grid 528  (overlays qn, safe: qn dead)
    gemm_mfma_k<64, 8, 5, false><<<528, 256, 0, stream>>>(
        hc, wout_h, b_out, nullptr, nullptr, r, nullptr, nullptr, 1024, 512);
    // fused q/k/v projection: N=1536, BN=128, grid 792; q/k hi/lo, v -> vt single
    gemm_mfma_k<128, 12, 4, false><<<792, 256, 0, stream>>>(
        r, wqkv_h, bqkv, nullptr, nullptr, qkv_h, qkv_l, vt, 512, QKV_N);
    // flash sliding-window attention -> ob single (overlays xm, dead)
    swa_flash_k<<<dim3(TT / 64, NHH, BB), 256, 0, stream>>>(qkv_h, qkv_l, vt, ob);
    // out = (ob @ wo + bo)[t >= M]: BN=64, grid 528
    gemm_mfma_k<64, 8, 0, true><<<528, 256, 0, stream>>>(
        ob, wo_h, bo, nullptr, out, nullptr, nullptr, nullptr, 512, 512);
}

// Round 16
// 131.850 us; speedup vs baseline: 3.6402x; 1.0951x over previous
//
#include <hip/hip_runtime.h>
#include <math.h>
#include <stdint.h>

#define BB 2
#define SS 2048
#define DD 512
#define HH 1024
#define MMETA 64
#define KCONV 4
#define NHH 8
#define DHH 64
#define WINN 256
#define TT (MMETA + SS)     // 2112
#define BT (BB * TT)        // 4224
#define QKV_N 1536

typedef __attribute__((ext_vector_type(8))) short short8v;   // 8 bf16 = 4 VGPR
typedef __attribute__((ext_vector_type(4))) float f32x4;

__device__ __forceinline__ unsigned short f2bf(float f) {
    union { float f; unsigned u; } c; c.f = f;
    unsigned u = c.u;
    unsigned r = (u + 0x7fffu + ((u >> 16) & 1u)) >> 16;   // RNE
    return (unsigned short)r;
}
__device__ __forceinline__ float bf2f(unsigned short h) {
    union { unsigned u; float f; } c; c.u = ((unsigned)h) << 16;
    return c.f;
}

__device__ __forceinline__ void gload_lds16(const void* g, void* l) {
    __builtin_amdgcn_global_load_lds(
        (const __attribute__((address_space(1))) unsigned int*)g,
        (__attribute__((address_space(3))) unsigned int*)l, 16, 0, 0);
}

// counted vmcnt wait (T4)
template<int N>
__device__ __forceinline__ void vm_wait() {
    if constexpr (N == 0)      asm volatile("s_waitcnt vmcnt(0)" ::: "memory");
    else if constexpr (N == 4) asm volatile("s_waitcnt vmcnt(4)" ::: "memory");
    else if constexpr (N == 6) asm volatile("s_waitcnt vmcnt(6)" ::: "memory");
    else static_assert(N == 0, "unsupported vmcnt");
}

// ---------------------------------------------------------------------------
// merged prep: 9x weight transpose (single bf16) | build_xm (single) | bias
// ---------------------------------------------------------------------------
struct WJobs {
    const float* W[9];
    unsigned short* Wh[9];
    int K[9];
    int N[9];
    int base[10];
};

__global__ __launch_bounds__(256) void prep_all_k(
    WJobs jb,
    const float* __restrict__ x, const float* __restrict__ meta,
    unsigned short* __restrict__ xh,
    const float* __restrict__ bq, const float* __restrict__ bk,
    const float* __restrict__ bv, float* __restrict__ bqkv)
{
    __shared__ float tile[64][65];
    const int bid = blockIdx.x;
    const int tid = threadIdx.x;

    if (bid < 1088) {
        int j = 0;
        while (bid >= jb.base[j + 1]) ++j;
        const int local = bid - jb.base[j];
        const int K = jb.K[j], N = jb.N[j];
        const int nx = N >> 6;
        const int k0 = (local / nx) * 64, n0 = (local % nx) * 64;
        const float* W = jb.W[j];
        unsigned short* Wh = jb.Wh[j];
        #pragma unroll
        for (int i = 0; i < 16; ++i) {
            int lin = i * 256 + tid;
            int kr = lin >> 6, nc = lin & 63;
            tile[kr][nc] = W[(size_t)(k0 + kr) * N + n0 + nc];
        }
        __syncthreads();
        #pragma unroll
        for (int i = 0; i < 16; ++i) {
            int lin = i * 256 + tid;
            int nr = lin >> 6, kc = lin & 63;
            Wh[(size_t)(n0 + nr) * K + k0 + kc] = f2bf(tile[kc][nr]);
        }
    } else if (bid < 3200) {
        int idx = (bid - 1088) * 256 + tid;   // float4 index over BT*128
        int row = idx >> 7, c4 = idx & 127;
        int b = row >= TT;
        int t = row - b * TT;
        float4 v = (t < MMETA) ? ((const float4*)(meta + (size_t)t * DD))[c4]
                               : ((const float4*)(x + ((size_t)b * SS + (t - MMETA)) * DD))[c4];
        ushort4 h;
        h.x = f2bf(v.x); h.y = f2bf(v.y); h.z = f2bf(v.z); h.w = f2bf(v.w);
        ((ushort4*)xh)[idx] = h;
    } else {
        int i = (bid - 3200) * 256 + tid;
        if (i < QKV_N) {
            float v;
            if (i < 512) v = bq[i];
            else if (i < 1024) v = bk[i - 512];
            else v = bv[i - 1024];
            bqkv[i] = v;
        }
    }
}

// ---------------------------------------------------------------------------
// MFMA GEMM: single bf16 A & W, BK=64 (2 k-halves per K-step).
//   128B LDS rows, sigma(r) = (r&7)<<4 swizzle (conflict-free, rule #21).
//   counted-vmcnt double-buffer (T4); grid 66*GN, XCD swizzle.
//   EPI: 0 bias->fp32; 4 qkv: cols<1024 -> hi/lo split, cols>=1024 -> vt single;
//        5 silu->single bf16; 6 res(single)+silu->single bf16
// ---------------------------------------------------------------------------
template<int BN, int GN, int EPI, bool DROPMETA>
__global__ __launch_bounds__(256, 3) void gemm_mfma_k(
    const unsigned short* __restrict__ Ah,
    const unsigned short* __restrict__ Wh,
    const float* __restrict__ bias,
    const unsigned short* __restrict__ resh,
    float* __restrict__ outf, unsigned short* __restrict__ outh,
    unsigned short* __restrict__ outl,
    unsigned short* __restrict__ vth,
    int K, int N)
{
    constexpr int BM = 64;
    constexpr int MF = 2;              // wave covers 32 rows
    constexpr int NF = BN / 32;        // wave covers BN/2 cols
    constexpr int ABYTES = BM * 128;   // 8 KB (64 rows x 64 k x 2B)
    constexpr int BBYTES = BN * 128;
    constexpr int BUFB = ABYTES + BBYTES;
    constexpr int LOADS = BUFB / 4096; // per-thread loads per stage (4 or 6)
    __shared__ short8v smem_v[(2 * BUFB) / 16];
    char* smem = (char*)smem_v;

    // XCD-chunk swizzle (bijective since NWG % 8 == 0)
    constexpr int NWG = 66 * GN;
    const int orig = blockIdx.x;
    const int swz = (orig & 7) * (NWG >> 3) + (orig >> 3);
    const int row0 = (swz / GN) * BM;
    const int n0 = (swz % GN) * BN;

    const int tid = threadIdx.x;
    const int l = tid & 63, wid = tid >> 6;
    const int wm = wid >> 1, wn = wid & 1;
    const int lr = l & 15, lg = l >> 4;

    const char* Ahg0 = (const char*)Ah + (size_t)row0 * K * 2;
    const char* Whg  = (const char*)Wh + (size_t)n0 * K * 2;

    // fragment read offsets: row r (128B), k-half h; sigma(r) = (r&7)<<4
    int a_off[MF][2], b_off[NF][2];
    #pragma unroll
    for (int mf = 0; mf < MF; ++mf) {
        int r = wm * 32 + mf * 16 + lr;
        #pragma unroll
        for (int h = 0; h < 2; ++h)
            a_off[mf][h] = r * 128 + ((h * 64 + lg * 16) ^ ((r & 7) << 4));
    }
    #pragma unroll
    for (int nf = 0; nf < NF; ++nf) {
        int r = wn * (BN / 2) + nf * 16 + lr;
        #pragma unroll
        for (int h = 0; h < 2; ++h)
            b_off[nf][h] = r * 128 + ((h * 64 + lg * 16) ^ ((r & 7) << 4));
    }

    f32x4 acc[MF][NF];
    #pragma unroll
    for (int mf = 0; mf < MF; ++mf)
        #pragma unroll
        for (int nf = 0; nf < NF; ++nf) acc[mf][nf] = (f32x4){0.f, 0.f, 0.f, 0.f};

    const int NT = K / 64;

    auto stage = [&](int buf, int t) {
        char* lb = smem + buf * BUFB;
        const size_t kb = (size_t)t * 128;
        #pragma unroll
        for (int it = 0; it < ABYTES / 4096; ++it) {
            int off = (it * 256 + tid) * 16;
            int row = off >> 7;
            int sc = (off & 127) ^ ((row & 7) << 4);
            size_t gb = (size_t)row * (K * 2) + kb + sc;
            gload_lds16(Ahg0 + gb, lb + off);
        }
        #pragma unroll
        for (int it = 0; it < BBYTES / 4096; ++it) {
            int off = (it * 256 + tid) * 16;
            int row = off >> 7;
            int sc = (off & 127) ^ ((row & 7) << 4);
            size_t gb = (size_t)row * (K * 2) + kb + sc;
            gload_lds16(Whg + gb, lb + ABYTES + off);
        }
    };

    stage(0, 0);

    int cur = 0;
    for (int t = 0; t < NT; ++t) {
        if (t + 1 < NT) {
            stage(cur ^ 1, t + 1);
            vm_wait<LOADS>();        // wait only tile t's loads; t+1 stays in flight
        } else {
            vm_wait<0>();
        }
        __builtin_amdgcn_s_barrier();
        __builtin_amdgcn_sched_barrier(0);

        char* lb = smem + cur * BUFB;
        __builtin_amdgcn_s_setprio(1);
        #pragma unroll
        for (int h = 0; h < 2; ++h) {
            short8v ah[MF], bh[NF];
            #pragma unroll
            for (int mf = 0; mf < MF; ++mf)
                ah[mf] = *(const short8v*)(lb + a_off[mf][h]);
            #pragma unroll
            for (int nf = 0; nf < NF; ++nf)
                bh[nf] = *(const short8v*)(lb + ABYTES + b_off[nf][h]);
            #pragma unroll
            for (int mf = 0; mf < MF; ++mf)
                #pragma unroll
                for (int nf = 0; nf < NF; ++nf)
                    acc[mf][nf] = __builtin_amdgcn_mfma_f32_16x16x32_bf16(ah[mf], bh[nf], acc[mf][nf], 0, 0, 0);
        }
        __builtin_amdgcn_s_setprio(0);
        __builtin_amdgcn_s_barrier();    // all reads of buf[cur] done before overwrite
        cur ^= 1;
    }

    // epilogue: C/D layout col = lane&15, row = (lane>>4)*4 + reg
    #pragma unroll
    for (int mf = 0; mf < MF; ++mf) {
        #pragma unroll
        for (int nf = 0; nf < NF; ++nf) {
            int col = n0 + wn * (BN / 2) + nf * 16 + lr;
            float bv = bias[col];
            if (EPI == 4 && col >= 1024) {
                // transposed v write: vt[d][token], single bf16
                unsigned short hv[4];
                #pragma unroll
                for (int j = 0; j < 4; ++j)
                    hv[j] = f2bf(acc[mf][nf][j] + bv);
                int dg = col - 1024;
                size_t tok = (size_t)row0 + wm * 32 + mf * 16 + lg * 4;
                *(ushort4*)(vth + (size_t)dg * BT + tok) = *(ushort4*)hv;
            } else {
                #pragma unroll
                for (int j = 0; j < 4; ++j) {
                    int row = row0 + wm * 32 + mf * 16 + lg * 4 + j;
                    float v = acc[mf][nf][j] + bv;
                    if (EPI == 5 || EPI == 6) v = v / (1.f + __expf(-v));
                    size_t idx = (size_t)row * N + col;
                    if (EPI == 6) v += bf2f(resh[idx]);
                    if (EPI == 0) {
                        if (DROPMETA) {
                            int b = row >= TT;
                            int t2 = row - b * TT;
                            if (t2 >= MMETA)
                                outf[((size_t)b * SS + (t2 - MMETA)) * N + col] = v;
                        } else {
                            outf[idx] = v;
                        }
                    } else if (EPI == 5 || EPI == 6) {
                        outh[idx] = f2bf(v);
                    } else {   // EPI == 4, q/k cols: hi/lo split
                        unsigned short hi = f2bf(v);
                        outh[idx] = hi;
                        outl[idx] = f2bf(v - bf2f(hi));
                    }
                }
            }
        }
    }
}

// ---------------------------------------------------------------------------
// causal depthwise conv (K=4) + L2 normalize; 8 rows/block; single bf16 out.
// ---------------------------------------------------------------------------
__global__ __launch_bounds__(256) void conv_norm8_k(
    const float* __restrict__ qlin, const float* __restrict__ convw,
    unsigned short* __restrict__ qh)
{
    __shared__ float qs[11][512];
    const int tid = threadIdx.x;
    const int r0 = blockIdx.x * 8;               // 2112 % 8 == 0: no batch straddle
    const int b = r0 >= TT;
    const int bstart = b * TT;

    const float4* ql4 = (const float4*)qlin;
    for (int i = tid; i < 11 * 128; i += 256) {
        int lrow = i >> 7, c4 = i & 127;
        int grow = r0 - 3 + lrow;
        float4 v = (grow >= bstart) ? ql4[(size_t)grow * 128 + c4]
                                    : (float4){0.f, 0.f, 0.f, 0.f};
        ((float4*)qs[lrow])[c4] = v;
    }
    __syncthreads();

    const int w = tid >> 6, lane = tid & 63;
    const int d0 = lane * 8;

    #pragma unroll
    for (int e = 0; e < 2; ++e) {
        const int lrow = w * 2 + e;              // 0..7
        const int rowg = r0 + lrow;
        float vals[8];
        #pragma unroll
        for (int j = 0; j < 8; ++j) vals[j] = 0.f;
        #pragma unroll
        for (int k = 0; k < KCONV; ++k) {
            const float* src = qs[lrow + k];
            const float* cw = convw + k * DD + d0;
            #pragma unroll
            for (int j = 0; j < 8; ++j)
                vals[j] += src[d0 + j] * cw[j];
        }
        float ss = 0.f;
        #pragma unroll
        for (int j = 0; j < 8; ++j) ss += vals[j] * vals[j];
        #pragma unroll
        for (int off = 32; off > 0; off >>= 1)
            ss += __shfl_xor(ss, off);
        float inv = 1.f / fmaxf(sqrtf(ss), 1e-12f);
        unsigned short hv[8];
        #pragma unroll
        for (int j = 0; j < 8; ++j)
            hv[j] = f2bf(vals[j] * inv);
        size_t base = (size_t)rowg * DD + d0;
        *(ushort4*)(qh + base) = *(ushort4*)hv;
        *(ushort4*)(qh + base + 4) = *(ushort4*)(hv + 4);
    }
}

// ---------------------------------------------------------------------------
// Flash sliding-window attention: Q/K hi/lo (bf16x3 QK^T), V single (1x PV).
//   K/V tiles double-buffered in LDS with counted vmcnt (T14/T4).
// ---------------------------------------------------------------------------
__global__ __launch_bounds__(256, 2) void swa_flash_k(
    const unsigned short* __restrict__ qkvh, const unsigned short* __restrict__ qkvl,
    const unsigned short* __restrict__ vth,
    unsigned short* __restrict__ oh)
{
    // LDS: 2 x (Kh 8192 | Kl 8192 | Vh 8192) | P 4x2304   = 58368 B
    __shared__ short8v lds_v[58368 / 16];
    char* lds = (char*)lds_v;
    char* P_lds = lds + 49152;

    const int tid = threadIdx.x;
    const int lane = tid & 63, w = tid >> 6;
    const int l15 = lane & 15, lg = lane >> 4;
    const int q0 = blockIdx.x * 64;
    const int h = blockIdx.y, b = blockIdx.z;
    const int rowbase = b * TT;

    const int qrow = rowbase + q0 + w * 16 + l15;
    short8v qhf[2], qlf[2];
    #pragma unroll
    for (int kh = 0; kh < 2; ++kh) {
        size_t off = (size_t)qrow * QKV_N + h * 64 + kh * 32 + lg * 8;
        qhf[kh] = *(const short8v*)(qkvh + off);
        qlf[kh] = *(const short8v*)(qkvl + off);
    }

    f32x4 o_acc[4];
    #pragma unroll
    for (int td = 0; td < 4; ++td) o_acc[td] = (f32x4){0.f, 0.f, 0.f, 0.f};
    float m_r[4], l_r[4];
    #pragma unroll
    for (int r = 0; r < 4; ++r) { m_r[r] = -1e30f; l_r[r] = 0.f; }

    char* Pw = P_lds + w * 2304;   // per-wave [16][72] bf16

    // stage K (hi/lo) + V^T tile kt into buffer buf (6 loads/thread)
    auto stage_kv = [&](int buf, int kt) {
        char* base = lds + buf * 24576;
        const int kst = q0 - 256 + kt * 64;
        #pragma unroll
        for (int it = 0; it < 2; ++it) {
            int lin = it * 256 + tid;
            int r = lin >> 3, seg = lin & 7;
            int colb = (seg * 16) ^ ((r & 7) << 4);
            size_t gb = ((size_t)(rowbase + kst + r) * QKV_N + 512 + h * 64) * 2 + colb;
            gload_lds16((const char*)qkvh + gb, base + lin * 16);
            gload_lds16((const char*)qkvl + gb, base + 8192 + lin * 16);
        }
        #pragma unroll
        for (int it = 0; it < 2; ++it) {
            int lin = it * 256 + tid;
            int dd = lin >> 3, seg = lin & 7;
            int colb = (seg * 16) ^ ((dd & 7) << 4);
            size_t gb = ((size_t)(h * 64 + dd) * BT + rowbase + kst) * 2 + colb;
            gload_lds16((const char*)vth + gb, base + 16384 + lin * 16);
        }
    };

    const int kt_min = (q0 >= 256) ? 0 : (256 - q0) / 64;
    stage_kv(0, kt_min);

    int bufi = 0;
    for (int kt = kt_min; kt < 5; ++kt) {
        const int kst = q0 - 256 + kt * 64;
        if (kt + 1 < 5) {
            stage_kv(bufi ^ 1, kt + 1);
            vm_wait<6>();            // current tile done; next stays in flight
        } else {
            vm_wait<0>();
        }
        __builtin_amdgcn_s_barrier();
        __builtin_amdgcn_sched_barrier(0);

        char* Kh_lds = lds + bufi * 24576;
        char* Kl_lds = Kh_lds + 8192;
        char* Vh_lds = Kh_lds + 16384;

        f32x4 s_fr[4];
        #pragma unroll
        for (int tj = 0; tj < 4; ++tj) s_fr[tj] = (f32x4){0.f, 0.f, 0.f, 0.f};
        #pragma unroll
        for (int tj = 0; tj < 4; ++tj) {
            int j = tj * 16 + l15;
            #pragma unroll
            for (int kh = 0; kh < 2; ++kh) {
                int colb = (kh * 64 + lg * 16) ^ ((j & 7) << 4);
                short8v kbh = *(const short8v*)(Kh_lds + j * 128 + colb);
                short8v kbl = *(const short8v*)(Kl_lds + j * 128 + colb);
                s_fr[tj] = __builtin_amdgcn_mfma_f32_16x16x32_bf16(qhf[kh], kbh, s_fr[tj], 0, 0, 0);
                s_fr[tj] = __builtin_amdgcn_mfma_f32_16x16x32_bf16(qhf[kh], kbl, s_fr[tj], 0, 0, 0);
                s_fr[tj] = __builtin_amdgcn_mfma_f32_16x16x32_bf16(qlf[kh], kbh, s_fr[tj], 0, 0, 0);
            }
        }
        #pragma unroll
        for (int tj = 0; tj < 4; ++tj) {
            int j = kst + tj * 16 + l15;
            #pragma unroll
            for (int r = 0; r < 4; ++r) {
                int i = q0 + w * 16 + lg * 4 + r;
                bool valid = (j <= i) && (i - j < WINN);
                s_fr[tj][r] = valid ? s_fr[tj][r] * 0.125f : -1e30f;
            }
        }
        float mx[4];
        #pragma unroll
        for (int r = 0; r < 4; ++r) {
            mx[r] = fmaxf(fmaxf(s_fr[0][r], s_fr[1][r]), fmaxf(s_fr[2][r], s_fr[3][r]));
            #pragma unroll
            for (int msk = 1; msk <= 8; msk <<= 1)
                mx[r] = fmaxf(mx[r], __shfl_xor(mx[r], msk));
            float mn = fmaxf(m_r[r], mx[r]);
            float sc = __expf(m_r[r] - mn);
            m_r[r] = mn;
            l_r[r] *= sc;
            #pragma unroll
            for (int td = 0; td < 4; ++td) o_acc[td][r] *= sc;
        }
        float rs[4] = {0.f, 0.f, 0.f, 0.f};
        #pragma unroll
        for (int tj = 0; tj < 4; ++tj) {
            #pragma unroll
            for (int r = 0; r < 4; ++r) {
                float p = __expf(s_fr[tj][r] - m_r[r]);
                rs[r] += p;
                ((unsigned short*)Pw)[(lg * 4 + r) * 72 + tj * 16 + l15] = f2bf(p);
            }
        }
        #pragma unroll
        for (int r = 0; r < 4; ++r) {
            #pragma unroll
            for (int msk = 1; msk <= 8; msk <<= 1)
                rs[r] += __shfl_xor(rs[r], msk);
            l_r[r] += rs[r];
        }
        short8v pa[2];
        #pragma unroll
        for (int jh = 0; jh < 2; ++jh)
            pa[jh] = *(const short8v*)(Pw + l15 * 144 + jh * 64 + lg * 16);
        #pragma unroll
        for (int td = 0; td < 4; ++td) {
            int drow = td * 16 + l15;
            #pragma unroll
            for (int jh = 0; jh < 2; ++jh) {
                int colb = (jh * 64 + lg * 16) ^ ((drow & 7) << 4);
                short8v vfh = *(const short8v*)(Vh_lds + drow * 128 + colb);
                o_acc[td] = __builtin_amdgcn_mfma_f32_16x16x32_bf16(pa[jh], vfh, o_acc[td], 0, 0, 0);
            }
        }
        __builtin_amdgcn_s_barrier();   // buffer reads done before re-stage
        bufi ^= 1;
    }

    #pragma unroll
    for (int r = 0; r < 4; ++r) {
        float inv = 1.f / l_r[r];
        int row = rowbase + q0 + w * 16 + lg * 4 + r;
        #pragma unroll
        for (int td = 0; td < 4; ++td) {
            float v = o_acc[td][r] * inv;
            oh[(size_t)row * DD + h * 64 + td * 16 + l15] = f2bf(v);
        }
    }
}

// ---------------------------------------------------------------------------
// Launch
// ---------------------------------------------------------------------------
extern "C" void kernel_launch(void* const* d_in, const int* in_sizes, int n_in,
                              void* d_out, int out_size, void* d_ws, size_t ws_size,
                              hipStream_t stream)
{
    const float* x       = (const float*)d_in[0];
    const float* meta    = (const float*)d_in[1];
    const float* qp_w    = (const float*)d_in[2];
    const float* qp_b    = (const float*)d_in[3];
    const float* qp_conv = (const float*)d_in[4];
    const float* w_in    = (const float*)d_in[5];
    const float* b_in    = (const float*)d_in[6];
    const float* w_hid   = (const float*)d_in[7];
    const float* b_hid   = (const float*)d_in[8];
    const float* w_out   = (const float*)d_in[9];
    const float* b_out   = (const float*)d_in[10];
    const float* wq      = (const float*)d_in[11];
    const float* bq      = (const float*)d_in[12];
    const float* wk      = (const float*)d_in[13];
    const float* bk      = (const float*)d_in[14];
    const float* wv      = (const float*)d_in[15];
    const float* bv      = (const float*)d_in[16];
    const float* wo      = (const float*)d_in[17];
    const float* bo      = (const float*)d_in[18];
    float* out = (float*)d_out;

    typedef unsigned short us;
    char* p = (char*)d_ws;
    auto alloc = [&](size_t n) { char* r = p; p += (n + 255) & ~(size_t)255; return r; };

    // weights: single bf16, transposed [N][K]
    us* wqp_h   = (us*)alloc(512 * 512 * 2);
    us* win_h   = (us*)alloc(512 * 1024 * 2);
    us* whid0_h = (us*)alloc(1024 * 1024 * 2);
    us* whid1_h = (us*)alloc(1024 * 1024 * 2);
    us* wout_h  = (us*)alloc(1024 * 512 * 2);
    us* wqkv_h  = (us*)alloc((size_t)QKV_N * 512 * 2);
    us* wo_h    = (us*)alloc(512 * 512 * 2);
    float* bqkv = (float*)alloc(QKV_N * 4);

    const size_t H512 = (size_t)BT * 512 * 2;    // 4.3 MB (bf16 plane, 512 cols)
    const size_t H1024 = (size_t)BT * 1024 * 2;  // 8.65 MB
    char* RA = alloc(H512);        // xm single -> later ob single
    char* RB = alloc((size_t)BT * 512 * 4);   // qlin fp32
    char* RC = alloc(H512);        // qn single -> r single
    char* RD1 = alloc(H1024);      // ha single -> hc single
    char* RD2 = alloc(H1024);      // hb single
    char* RF = alloc(2 * (size_t)BT * QKV_N * 2);   // qkv hi/lo (q,k cols used)
    char* RE = alloc(H512);        // vt single ([512][BT])

    us* xm = (us*)RA;
    float* qlin = (float*)RB;
    us* qn = (us*)RC;
    us* ha = (us*)RD1;
    us* hb = (us*)RD2;
    us* hc = (us*)RD1;    // overlay ha (dead after whid0)
    us* r  = qn;          // overlay qn (dead after win GEMM)
    us* qkv_h = (us*)RF;  us* qkv_l = (us*)(RF + (size_t)BT * QKV_N * 2);
    us* vt = (us*)RE;
    us* ob = (us*)RA;     // overlay xm (dead after qlin GEMM)

    // --- merged prep: wsplit (1088) + build_xm (2112) + bias (6) ---
    WJobs jb;
    const float* Ws[9]   = {qp_w, w_in, w_hid, w_hid + (size_t)1024 * 1024, w_out,
                            wq, wk, wv, wo};
    us* Whs[9] = {wqp_h, win_h, whid0_h, whid1_h, wout_h,
                  wqkv_h, wqkv_h + 512 * 512, wqkv_h + 2 * 512 * 512, wo_h};
    int Ks[9] = {512, 512, 1024, 1024, 1024, 512, 512, 512, 512};
    int Ns[9] = {512, 1024, 1024, 1024, 512, 512, 512, 512, 512};
    int acc_t = 0;
    for (int j = 0; j < 9; ++j) {
        jb.W[j] = Ws[j]; jb.Wh[j] = Whs[j];
        jb.K[j] = Ks[j]; jb.N[j] = Ns[j];
        jb.base[j] = acc_t;
        acc_t += (Ks[j] / 64) * (Ns[j] / 64);
    }
    jb.base[9] = acc_t;    // 1088
    prep_all_k<<<3206, 256, 0, stream>>>(jb, x, meta, xm, bq, bk, bv, bqkv);

    // --- pipeline (single-A GEMMs, BK=64) ---
    // qlin = xm @ qp_w + b (fp32 out): N=512, BN=64, grid 528
    gemm_mfma_k<64, 8, 0, false><<<528, 256, 0, stream>>>(
        xm, wqp_h, qp_b, nullptr, qlin, nullptr, nullptr, nullptr, 512, 512);
    conv_norm8_k<<<BT / 8, 256, 0, stream>>>(qlin, qp_conv, qn);
    // ha = silu(qn @ w_in + b_in): BN=128, grid 528
    gemm_mfma_k<128, 8, 5, false><<<528, 256, 0, stream>>>(
        qn, win_h, b_in, nullptr, nullptr, ha, nullptr, nullptr, 512, 1024);
    // hb = ha + silu(ha @ whid0 + b0)
    gemm_mfma_k<128, 8, 6, false><<<528, 256, 0, stream>>>(
        ha, whid0_h, b_hid, ha, nullptr, hb, nullptr, nullptr, 1024, 1024);
    // hc = hb + silu(hb @ whid1 + b1)
    gemm_mfma_k<128, 8, 6, false><<<528, 256, 0, stream>>>(
        hb, whid1_h, b_hid + HH, hb, nullptr, hc, nullptr, nullptr, 1024, 1024);
    // r = silu(hc @ w_out + b_out): BN=64, grid 528
    gemm_mfma_k<64, 8, 5, false><<<528, 256, 0, stream>>>(
        hc, wout_h, b_out, nullptr, nullptr, r, nullptr, nullptr, 1024, 512);
    // fused q/k/v projection: N=1536, BN=128, grid 792; q/k hi/lo, v -> vt single
    gemm_mfma_k<128, 12, 4, false><<<792, 256, 0, stream>>>(
        r, wqkv_h, bqkv, nullptr, nullptr, qkv_h, qkv_l, vt, 512, QKV_N);
    // flash sliding-window attention -> ob single
    swa_flash_k<<<dim3(TT / 64, NHH, BB), 256, 0, stream>>>(qkv_h, qkv_l, vt, ob);
    // out = (ob @ wo + bo)[t >= M]: BN=64, grid 528
    gemm_mfma_k<64, 8, 0, true><<<528, 256, 0, stream>>>(
        ob, wo_h, bo, nullptr, out, nullptr, nullptr, nullptr, 512, 512);
}